// Round 6
// baseline (330.818 us; speedup 1.0000x reference)
//
#include <hip/hip_runtime.h>
#include <math.h>

#define B_   32
#define C_   64
#define F_   128
#define TP_  32
#define G_   (B_*TP_)      // 1024 graphs
#define NHID 256
#define NOUT 128
#define E_   512
#define K1_  52            // ceil(0.8*64)
#define K2_  42            // ceil(0.8*52)
#define N2_  (G_*K1_)      // 53248 rows layer 2

// -------- build shared 64x64 A1 (edge-weight norm) and As1 (binary norm) -------------
__global__ __launch_bounds__(256) void build_A1(const int* __restrict__ ei,
                                                const float* __restrict__ ew,
                                                float* __restrict__ A1,
                                                float* __restrict__ As1) {
  __shared__ float A1s[C_*C_], As1s[C_*C_];
  __shared__ float dg[C_], dgs[C_], dis[C_], diss[C_];
  int t = threadIdx.x;
  for (int i = t; i < C_*C_; i += 256) { A1s[i] = 0.f; As1s[i] = 0.f; }
  if (t < C_) { dg[t] = 1.f; dgs[t] = 1.f; }   // self-loop weight 1
  int r0[2], c0[2]; float w0[2];
#pragma unroll
  for (int p = 0; p < 2; ++p) {
    int e = t + p*256;
    r0[p] = ei[e]; c0[p] = ei[E_ + e]; w0[p] = ew[e];
  }
  __syncthreads();
#pragma unroll
  for (int p = 0; p < 2; ++p) {
    atomicAdd(&dg[c0[p]], w0[p]);
    atomicAdd(&dgs[c0[p]], 1.f);
  }
  __syncthreads();
  if (t < C_) { dis[t] = rsqrtf(dg[t]); diss[t] = rsqrtf(dgs[t]); }
  __syncthreads();
#pragma unroll
  for (int p = 0; p < 2; ++p) {
    int r = r0[p], c = c0[p];
    atomicAdd(&A1s[c*C_ + r],  dis[r] * w0[p] * dis[c]);
    atomicAdd(&As1s[c*C_ + r], diss[r] * diss[c]);
  }
  if (t < C_) {
    atomicAdd(&A1s[t*C_ + t],  dis[t] * dis[t]);
    atomicAdd(&As1s[t*C_ + t], diss[t] * diss[t]);
  }
  __syncthreads();
  for (int i = t; i < C_*C_; i += 256) { A1[i] = A1s[i]; As1[i] = As1s[i]; }
}

// ---- preagg: xa2[b,c,f,tp] = sum_j A1[c,j] * h[b,j,f,tp]  (per-b, (f,tp) cols) ------
__global__ __launch_bounds__(256) void preagg_b(const float* __restrict__ h,
                                                const float* __restrict__ A1,
                                                float* __restrict__ xa2) {
  int bid = blockIdx.x; int b = bid >> 5, q = bid & 31;   // q: 128-col chunk of 4096
  __shared__ float At[64*68];                              // A1 transposed [j][c]
  __shared__ __align__(16) float Hs[64*132];
  int t = threadIdx.x;
#pragma unroll
  for (int p = 0; p < 16; ++p) {
    int m = t + p*256;                      // A1[c*64+j]
    At[(m & 63)*68 + (m >> 6)] = A1[m];
  }
  const float* hb = h + ((size_t)b*64)*4096 + q*128;
#pragma unroll
  for (int p = 0; p < 8; ++p) {
    int idx = t + p*256;                    // 2048 float4 tiles: 64 j x 32 f4
    int j = idx >> 5, f4 = idx & 31;
    *(float4*)&Hs[j*132 + f4*4] = *(const float4*)(hb + (size_t)j*4096 + f4*4);
  }
  __syncthreads();
  int tx = t & 31, ty = t >> 5;             // tx: f4 col, ty: 8-row c block
  float acc[8][4] = {};
  for (int j = 0; j < 64; ++j) {
    float a[8];
    *(float4*)&a[0] = *(const float4*)&At[j*68 + ty*8];
    *(float4*)&a[4] = *(const float4*)&At[j*68 + ty*8 + 4];
    float4 hv = *(const float4*)&Hs[j*132 + tx*4];
#pragma unroll
    for (int i = 0; i < 8; ++i) {
      acc[i][0] = fmaf(a[i], hv.x, acc[i][0]);
      acc[i][1] = fmaf(a[i], hv.y, acc[i][1]);
      acc[i][2] = fmaf(a[i], hv.z, acc[i][2]);
      acc[i][3] = fmaf(a[i], hv.w, acc[i][3]);
    }
  }
  float* outp = xa2 + (((size_t)b*64) << 12) + q*128 + tx*4;
#pragma unroll
  for (int i = 0; i < 8; ++i) {
    int c = ty*8 + i;
    *(float4*)(outp + ((size_t)c << 12)) =
        make_float4(acc[i][0], acc[i][1], acc[i][2], acc[i][3]);
  }
}

// ---- gemm1e: y1 = prelu(bn(xa @ W1 + b1)); per-row partial pool1 dots ---------------
// ONE WAVE per block (64 thr): BM=64 rows (2 c x 32 tp), BN=128 cols, 16x8 microtile.
// 1-wave blocks -> no barrier lockstep; 3 resident waves/SIMD hide LDS latency.
__global__ __launch_bounds__(64, 3) void gemm1e(const float* __restrict__ xa2,
                                                const float* __restrict__ W1,
                                                const float* __restrict__ gc1b,
                                                const float* __restrict__ g1,
                                                const float* __restrict__ be1,
                                                const float* __restrict__ mu1,
                                                const float* __restrict__ v1,
                                                const float* __restrict__ pa1,
                                                const float* __restrict__ pw1,
                                                float* __restrict__ y1,
                                                float* __restrict__ dots2) {
  __shared__ __align__(16) float As[16*68];    // [k][row], row = c_local*32+tp
  __shared__ __align__(16) float Bs[16*132];   // [k][col]
  int t = threadIdx.x;
  int mb = blockIdx.x; int b = mb >> 5, c0 = (mb & 31) * 2;
  int nb = blockIdx.y; int col0 = nb * 128;
  int tx = t & 15, ty = t >> 4;                // ty in 0..3
  float acc[16][8] = {};
  const float* abase = xa2 + (((size_t)(b*64 + c0)) << 12);
  for (int k0 = 0; k0 < 128; k0 += 16) {
#pragma unroll
    for (int p = 0; p < 4; ++p) {              // 256 float4: 16 k x 16 row4
      int idx = t + p*64;
      int kl = idx >> 4, rr4 = idx & 15;
      int cl = rr4 >> 3, tp0 = (rr4 & 7)*4;
      float4 av = *(const float4*)(abase + ((size_t)cl << 12) + (k0 + kl)*32 + tp0);
      *(float4*)&As[kl*68 + rr4*4] = av;
    }
#pragma unroll
    for (int p = 0; p < 8; ++p) {              // 512 float4: 16 k x 32 col4
      int idx = t + p*64;
      int rk = idx >> 5, cn = (idx & 31)*4;
      *(float4*)&Bs[rk*132 + cn] = *(const float4*)(W1 + (size_t)(k0+rk)*NHID + col0 + cn);
    }
    __syncthreads();
#pragma unroll
    for (int kk = 0; kk < 16; ++kk) {
      float a[16], bb[8];
#pragma unroll
      for (int qd = 0; qd < 4; ++qd)
        *(float4*)&a[4*qd] = *(const float4*)&As[kk*68 + qd*16 + 4*ty];
      *(float4*)&bb[0] = *(const float4*)&Bs[kk*132 + 4*tx];
      *(float4*)&bb[4] = *(const float4*)&Bs[kk*132 + 64 + 4*tx];
#pragma unroll
      for (int i = 0; i < 16; ++i)
#pragma unroll
        for (int j = 0; j < 8; ++j)
          acc[i][j] = fmaf(a[i], bb[j], acc[i][j]);
    }
    __syncthreads();
  }
  // epilogue constants (late, to keep loop VGPR pressure low)
  float4 scv[2], shv[2], pwv[2];
#pragma unroll
  for (int jh = 0; jh < 2; ++jh) {
    int col = col0 + jh*64 + 4*tx;
    float4 gv = *(const float4*)(g1 + col);
    float4 vv = *(const float4*)(v1 + col);
    float4 bv = *(const float4*)(be1 + col);
    float4 mv = *(const float4*)(mu1 + col);
    float4 b0 = *(const float4*)(gc1b + col);
    float4 s;
    s.x = gv.x * rsqrtf(vv.x + 1e-5f); s.y = gv.y * rsqrtf(vv.y + 1e-5f);
    s.z = gv.z * rsqrtf(vv.z + 1e-5f); s.w = gv.w * rsqrtf(vv.w + 1e-5f);
    scv[jh] = s;
    shv[jh] = make_float4((b0.x - mv.x)*s.x + bv.x, (b0.y - mv.y)*s.y + bv.y,
                          (b0.z - mv.z)*s.z + bv.z, (b0.w - mv.w)*s.w + bv.w);
    pwv[jh] = *(const float4*)(pw1 + col);
  }
  float a1v = pa1[0];
#pragma unroll
  for (int qd = 0; qd < 4; ++qd)
#pragma unroll
    for (int i = 0; i < 4; ++i) {
      int rr = qd*16 + 4*ty + i;
      int cl = rr >> 5, tp = rr & 31;
      size_t R = (size_t)(b*32 + tp)*64 + c0 + cl;
      float dpart = 0.f;
#pragma unroll
      for (int jh = 0; jh < 2; ++jh) {
        float4 o;
        o.x = acc[qd*4+i][jh*4+0]*scv[jh].x + shv[jh].x;
        o.y = acc[qd*4+i][jh*4+1]*scv[jh].y + shv[jh].y;
        o.z = acc[qd*4+i][jh*4+2]*scv[jh].z + shv[jh].z;
        o.w = acc[qd*4+i][jh*4+3]*scv[jh].w + shv[jh].w;
        o.x = o.x >= 0.f ? o.x : a1v*o.x; o.y = o.y >= 0.f ? o.y : a1v*o.y;
        o.z = o.z >= 0.f ? o.z : a1v*o.z; o.w = o.w >= 0.f ? o.w : a1v*o.w;
        *(float4*)(y1 + R*NHID + col0 + jh*64 + 4*tx) = o;
        dpart += o.x*pwv[jh].x + o.y*pwv[jh].y + o.z*pwv[jh].z + o.w*pwv[jh].w;
      }
      dpart += __shfl_xor(dpart, 1);
      dpart += __shfl_xor(dpart, 2);
      dpart += __shfl_xor(dpart, 4);
      dpart += __shfl_xor(dpart, 8);
      if (tx == 0) dots2[R*2 + nb] = dpart;
    }
}

// ---- pool1s: scores = As1 @ dots + b; stable top-52; emit rowsrc/rowgate/nidx -------
__global__ __launch_bounds__(256) void pool1s(const float* __restrict__ dots2,
                                              const float* __restrict__ As1,
                                              const float* __restrict__ p1b,
                                              int* __restrict__ rowsrc,
                                              float* __restrict__ rowgate,
                                              int* __restrict__ nidx) {
  int g = blockIdx.x, t = threadIdx.x;
  __shared__ float As1s[64*65];
  __shared__ float sp[64], s[64];
  __shared__ int perm[K1_];
  __shared__ float gate[K1_];
  for (int i = t; i < 4096; i += 256)
    As1s[(i >> 6)*65 + (i & 63)] = As1[i];
  if (t < 64) sp[t] = dots2[(g*64 + t)*2] + dots2[(g*64 + t)*2 + 1];
  __syncthreads();
  if (t < 64) {
    float acc = p1b[0];
    for (int j = 0; j < 64; ++j) acc = fmaf(As1s[t*65 + j], sp[j], acc);
    s[t] = acc;
  }
  __syncthreads();
  if (t < 64) {
    float si = s[t];
    int rank = 0;
    for (int j = 0; j < 64; ++j) {
      float sj = s[j];
      rank += (sj > si) || (sj == si && j < t);
    }
    nidx[g*64 + t] = (rank < K1_) ? rank : -1;
    if (rank < K1_) { perm[rank] = t; gate[rank] = tanhf(si); }
  }
  __syncthreads();
  if (t < K1_) {
    rowsrc[g*K1_ + t]  = g*64 + perm[t];
    rowgate[g*K1_ + t] = gate[t];
  }
}

// ---- gemm2g: xw2 = (gathered, gated y1) @ W2 ---------------------------------------
// ONE WAVE per block: BM=64 gathered rows, BN=128 (=NOUT), 16x8 microtile, K=256.
__global__ __launch_bounds__(64, 3) void gemm2g(const float* __restrict__ y1,
                                                const int* __restrict__ rowsrc,
                                                const float* __restrict__ rowgate,
                                                const float* __restrict__ W2,
                                                float* __restrict__ xw2) {
  __shared__ __align__(16) float As[16*68];
  __shared__ __align__(16) float Bs[16*132];
  int t = threadIdx.x;
  int row0 = blockIdx.x * 64;
  int tx = t & 15, ty = t >> 4;
  float acc[16][8] = {};
  for (int k0 = 0; k0 < NHID; k0 += 16) {
#pragma unroll
    for (int p = 0; p < 4; ++p) {              // 256 float4 = 64 rows x 4 f4
      int idx = t + p*64;
      int rm = idx >> 2, tq = idx & 3;
      int sr = rowsrc[row0 + rm];
      float gt = rowgate[row0 + rm];
      float4 av = *(const float4*)(y1 + (size_t)sr * NHID + k0 + 4*tq);
      As[(4*tq+0)*68 + rm] = av.x * gt; As[(4*tq+1)*68 + rm] = av.y * gt;
      As[(4*tq+2)*68 + rm] = av.z * gt; As[(4*tq+3)*68 + rm] = av.w * gt;
    }
#pragma unroll
    for (int p = 0; p < 8; ++p) {              // 512 float4: 16 k x 32 col4
      int idx = t + p*64;
      int rk = idx >> 5, cn = (idx & 31)*4;
      *(float4*)&Bs[rk*132 + cn] = *(const float4*)(W2 + (size_t)(k0 + rk)*NOUT + cn);
    }
    __syncthreads();
#pragma unroll
    for (int kk = 0; kk < 16; ++kk) {
      float a[16], bb[8];
#pragma unroll
      for (int qd = 0; qd < 4; ++qd)
        *(float4*)&a[4*qd] = *(const float4*)&As[kk*68 + qd*16 + 4*ty];
      *(float4*)&bb[0] = *(const float4*)&Bs[kk*132 + 4*tx];
      *(float4*)&bb[4] = *(const float4*)&Bs[kk*132 + 64 + 4*tx];
#pragma unroll
      for (int i = 0; i < 16; ++i)
#pragma unroll
        for (int j = 0; j < 8; ++j)
          acc[i][j] = fmaf(a[i], bb[j], acc[i][j]);
    }
    __syncthreads();
  }
#pragma unroll
  for (int qd = 0; qd < 4; ++qd)
#pragma unroll
    for (int i = 0; i < 4; ++i) {
      int r = row0 + qd*16 + 4*ty + i;
#pragma unroll
      for (int jh = 0; jh < 2; ++jh) {
        float4 v = make_float4(acc[qd*4+i][jh*4+0], acc[qd*4+i][jh*4+1],
                               acc[qd*4+i][jh*4+2], acc[qd*4+i][jh*4+3]);
        *(float4*)(xw2 + (size_t)r * NOUT + jh*64 + 4*tx) = v;
      }
    }
}

// ---- mega2r: build A2/As2 + agg+BN+PReLU (y2 in regs) + dots + scores + rank-out ----
__global__ __launch_bounds__(256) void mega2r(const int* __restrict__ ei,
                                              const float* __restrict__ ew,
                                              const int* __restrict__ nidx,
                                              const float* __restrict__ xw2,
                                              const float* __restrict__ gc2b,
                                              const float* __restrict__ g2,
                                              const float* __restrict__ be2,
                                              const float* __restrict__ mu2,
                                              const float* __restrict__ v2,
                                              const float* __restrict__ pa2,
                                              const float* __restrict__ pw2,
                                              const float* __restrict__ p2b,
                                              float* __restrict__ out) {
  int g = blockIdx.x, t = threadIdx.x;
  __shared__ float A2t[64*68];                 // [j][c] zero-padded
  __shared__ float As2s[K1_*K1_];
  __shared__ __align__(16) float xs[K1_*132];
  __shared__ float dg[K1_], dgs[K1_], dis[K1_], diss[K1_], d[K1_], s[K1_], gA[K1_];
  __shared__ int nm[C_], rankA[K1_];
  __shared__ float4 zpart[8][32];

  for (int i = t; i < 64*68; i += 256) A2t[i] = 0.f;
  for (int i = t; i < K1_*K1_; i += 256) As2s[i] = 0.f;
  if (t < C_) nm[t] = nidx[g*C_ + t];
  if (t < K1_) { dg[t] = 1.f; dgs[t] = 1.f; }
  for (int p = 0; p < 7; ++p) {
    int idx = t + p*256;
    if (idx < K1_*32) {
      int r = idx >> 5, f4 = idx & 31;
      *(float4*)&xs[r*132 + f4*4] =
          *(const float4*)(xw2 + ((size_t)g*K1_ + r)*NOUT + f4*4);
    }
  }
  int eR[2], eC[2]; float eW[2];
#pragma unroll
  for (int p = 0; p < 2; ++p) {
    int e = t + p*256;
    eR[p] = ei[e]; eC[p] = ei[E_ + e]; eW[p] = ew[e];
  }
  __syncthreads();
  int nr[2], nc[2]; bool val[2];
#pragma unroll
  for (int p = 0; p < 2; ++p) {
    nr[p] = nm[eR[p]]; nc[p] = nm[eC[p]];
    val[p] = (nr[p] >= 0) && (nc[p] >= 0);
    if (val[p]) { atomicAdd(&dg[nc[p]], eW[p]); atomicAdd(&dgs[nc[p]], 1.f); }
  }
  __syncthreads();
  if (t < K1_) { dis[t] = rsqrtf(dg[t]); diss[t] = rsqrtf(dgs[t]); }
  __syncthreads();
#pragma unroll
  for (int p = 0; p < 2; ++p) {
    if (val[p]) {
      atomicAdd(&A2t[nr[p]*68 + nc[p]],  dis[nr[p]] * eW[p] * dis[nc[p]]);
      atomicAdd(&As2s[nc[p]*K1_ + nr[p]], diss[nr[p]] * diss[nc[p]]);
    }
  }
  if (t < K1_) {
    atomicAdd(&A2t[t*68 + t],   dis[t]*dis[t]);
    atomicAdd(&As2s[t*K1_ + t], diss[t]*diss[t]);
  }
  __syncthreads();
  // agg: rows c = ty*8+i, cols 4*tx
  int tx = t & 31, ty = t >> 5;
  float4 scv, shv, pwv;
  {
    int col = 4*tx;
    float4 gv = *(const float4*)(g2 + col);
    float4 vv = *(const float4*)(v2 + col);
    float4 bv = *(const float4*)(be2 + col);
    float4 mv = *(const float4*)(mu2 + col);
    float4 b0 = *(const float4*)(gc2b + col);
    scv.x = gv.x * rsqrtf(vv.x + 1e-5f); scv.y = gv.y * rsqrtf(vv.y + 1e-5f);
    scv.z = gv.z * rsqrtf(vv.z + 1e-5f); scv.w = gv.w * rsqrtf(vv.w + 1e-5f);
    shv = make_float4((b0.x - mv.x)*scv.x + bv.x, (b0.y - mv.y)*scv.y + bv.y,
                      (b0.z - mv.z)*scv.z + bv.z, (b0.w - mv.w)*scv.w + bv.w);
    pwv = *(const float4*)(pw2 + col);
  }
  float a2v = pa2[0];
  float acc[8][4] = {};
  for (int j = 0; j < K1_; ++j) {
    float a[8];
    *(float4*)&a[0] = *(const float4*)&A2t[j*68 + ty*8];
    *(float4*)&a[4] = *(const float4*)&A2t[j*68 + ty*8 + 4];
    float4 xv = *(const float4*)&xs[j*132 + tx*4];
#pragma unroll
    for (int i = 0; i < 8; ++i) {
      acc[i][0] = fmaf(a[i], xv.x, acc[i][0]);
      acc[i][1] = fmaf(a[i], xv.y, acc[i][1]);
      acc[i][2] = fmaf(a[i], xv.z, acc[i][2]);
      acc[i][3] = fmaf(a[i], xv.w, acc[i][3]);
    }
  }
  // BN + PReLU in registers (y2 never leaves the block); node dots
#pragma unroll
  for (int i = 0; i < 8; ++i) {
    int c = ty*8 + i;
    if (c < K1_) {
      float4 o;
      o.x = acc[i][0]*scv.x + shv.x; o.y = acc[i][1]*scv.y + shv.y;
      o.z = acc[i][2]*scv.z + shv.z; o.w = acc[i][3]*scv.w + shv.w;
      o.x = o.x >= 0.f ? o.x : a2v*o.x; o.y = o.y >= 0.f ? o.y : a2v*o.y;
      o.z = o.z >= 0.f ? o.z : a2v*o.z; o.w = o.w >= 0.f ? o.w : a2v*o.w;
      acc[i][0] = o.x; acc[i][1] = o.y; acc[i][2] = o.z; acc[i][3] = o.w;
      float dp = o.x*pwv.x + o.y*pwv.y + o.z*pwv.z + o.w*pwv.w;
      dp += __shfl_xor(dp, 1);
      dp += __shfl_xor(dp, 2);
      dp += __shfl_xor(dp, 4);
      dp += __shfl_xor(dp, 8);
      dp += __shfl_xor(dp, 16);
      if (tx == 0) d[c] = dp;
    }
  }
  __syncthreads();
  if (t < K1_) {
    float sv = p2b[0];
    for (int j = 0; j < K1_; ++j) sv = fmaf(As2s[t*K1_ + j], d[j], sv);
    s[t] = sv;
  }
  __syncthreads();
  if (t < K1_) {
    float si = s[t];
    int rank = 0;
    for (int j = 0; j < K1_; ++j) {
      float sj = s[j];
      rank += (sj > si) || (sj == si && j < t);
    }
    rankA[t] = rank;
    gA[t] = tanhf(si);
  }
  __syncthreads();
  // rank-directed output: row c -> slot rankA[c] if selected
  float4 zp = make_float4(0.f, 0.f, 0.f, 0.f);
#pragma unroll
  for (int i = 0; i < 8; ++i) {
    int c = ty*8 + i;
    if (c < K1_) {
      int r = rankA[c];
      if (r < K2_) {
        float gt = gA[c];
        float4 v = make_float4(acc[i][0]*gt, acc[i][1]*gt, acc[i][2]*gt, acc[i][3]*gt);
        *(float4*)(out + ((size_t)g*K2_ + r)*NOUT + 4*tx) = v;
        zp.x += v.x; zp.y += v.y; zp.z += v.z; zp.w += v.w;
      }
    }
  }
  zpart[ty][tx] = zp;
  __syncthreads();
  if (t < 32) {
    float4 z = make_float4(0.f, 0.f, 0.f, 0.f);
#pragma unroll
    for (int k = 0; k < 8; ++k) {
      float4 v = zpart[k][t];
      z.x += v.x; z.y += v.y; z.z += v.z; z.w += v.w;
    }
    const float inv = 1.0f / (float)K2_;
    z.x *= inv; z.y *= inv; z.z *= inv; z.w *= inv;
    *(float4*)(out + (size_t)G_*K2_*NOUT + (size_t)g*NOUT + 4*t) = z;
  }
}

extern "C" void kernel_launch(void* const* d_in, const int* in_sizes, int n_in,
                              void* d_out, int out_size, void* d_ws, size_t ws_size,
                              hipStream_t stream) {
  const float* h    = (const float*)d_in[0];
  const int*   ei   = (const int*)  d_in[1];
  const float* ew   = (const float*)d_in[2];
  const float* gc1w = (const float*)d_in[3];
  const float* gc1b = (const float*)d_in[4];
  const float* bn1g = (const float*)d_in[5];
  const float* bn1b = (const float*)d_in[6];
  const float* bn1m = (const float*)d_in[7];
  const float* bn1v = (const float*)d_in[8];
  const float* pr1a = (const float*)d_in[9];
  const float* p1w  = (const float*)d_in[10];
  const float* p1b  = (const float*)d_in[11];
  const float* gc2w = (const float*)d_in[12];
  const float* gc2b = (const float*)d_in[13];
  const float* bn2g = (const float*)d_in[14];
  const float* bn2b = (const float*)d_in[15];
  const float* bn2m = (const float*)d_in[16];
  const float* bn2v = (const float*)d_in[17];
  const float* pr2a = (const float*)d_in[18];
  const float* p2w  = (const float*)d_in[19];
  const float* p2b  = (const float*)d_in[20];

  float* w = (float*)d_ws;
  // float offsets
  float* A1      = w;                       // 4096
  float* As1     = w + 4096;                // 4096
  float* dots2   = w + 8192;                // 131072 (65536 x 2)
  int*   nidx    = (int*)(w + 139264);      // 65536
  int*   rowsrc  = (int*)(w + 204800);      // 53248
  float* rowgate = w + 258048;              // 53248
  float* xa2     = w + 327680;              // 8388608  (32*64*128*32)
  float* y1      = w + 8716288;             // 16777216 (65536*256)  end 25493504 fl
  float* xw2     = xa2;                     // 6815744 <= 8388608 (xa2 dead after gemm1e)

  build_A1<<<1, 256, 0, stream>>>(ei, ew, A1, As1);
  preagg_b<<<1024, 256, 0, stream>>>(h, A1, xa2);
  gemm1e<<<dim3(1024, 2), 64, 0, stream>>>(xa2, gc1w, gc1b, bn1g, bn1b, bn1m, bn1v,
                                           pr1a, p1w, y1, dots2);
  pool1s<<<G_, 256, 0, stream>>>(dots2, As1, p1b, rowsrc, rowgate, nidx);
  gemm2g<<<832, 64, 0, stream>>>(y1, rowsrc, rowgate, gc2w, xw2);
  mega2r<<<G_, 256, 0, stream>>>(ei, ew, nidx, xw2, gc2b, bn2g, bn2b, bn2m, bn2v,
                                 pr2a, p2w, p2b, (float*)d_out);
}

// Round 7
// 181.515 us; speedup vs baseline: 1.8225x; 1.8225x over previous
//
#include <hip/hip_runtime.h>
#include <math.h>

#define B_   32
#define C_   64
#define F_   128
#define TP_  32
#define G_   (B_*TP_)      // 1024 graphs
#define NHID 256
#define NOUT 128
#define E_   512
#define K1_  52            // ceil(0.8*64)
#define K2_  42            // ceil(0.8*52)
#define N2_  (G_*K1_)      // 53248 rows layer 2

// -------- build shared 64x64 A1 (edge-weight norm) and As1 (binary norm) -------------
__global__ __launch_bounds__(256) void build_A1(const int* __restrict__ ei,
                                                const float* __restrict__ ew,
                                                float* __restrict__ A1,
                                                float* __restrict__ As1) {
  __shared__ float A1s[C_*C_], As1s[C_*C_];
  __shared__ float dg[C_], dgs[C_], dis[C_], diss[C_];
  int t = threadIdx.x;
  for (int i = t; i < C_*C_; i += 256) { A1s[i] = 0.f; As1s[i] = 0.f; }
  if (t < C_) { dg[t] = 1.f; dgs[t] = 1.f; }   // self-loop weight 1
  int r0[2], c0[2]; float w0[2];
#pragma unroll
  for (int p = 0; p < 2; ++p) {
    int e = t + p*256;
    r0[p] = ei[e]; c0[p] = ei[E_ + e]; w0[p] = ew[e];
  }
  __syncthreads();
#pragma unroll
  for (int p = 0; p < 2; ++p) {
    atomicAdd(&dg[c0[p]], w0[p]);
    atomicAdd(&dgs[c0[p]], 1.f);
  }
  __syncthreads();
  if (t < C_) { dis[t] = rsqrtf(dg[t]); diss[t] = rsqrtf(dgs[t]); }
  __syncthreads();
#pragma unroll
  for (int p = 0; p < 2; ++p) {
    int r = r0[p], c = c0[p];
    atomicAdd(&A1s[c*C_ + r],  dis[r] * w0[p] * dis[c]);
    atomicAdd(&As1s[c*C_ + r], diss[r] * diss[c]);
  }
  if (t < C_) {
    atomicAdd(&A1s[t*C_ + t],  dis[t] * dis[t]);
    atomicAdd(&As1s[t*C_ + t], diss[t] * diss[t]);
  }
  __syncthreads();
  for (int i = t; i < C_*C_; i += 256) { A1[i] = A1s[i]; As1[i] = As1s[i]; }
}

// ---- preagg: xa2[b,c,f,tp] = sum_j A1[c,j] * h[b,j,f,tp]  (per-b, (f,tp) cols) ------
__global__ __launch_bounds__(256) void preagg_b(const float* __restrict__ h,
                                                const float* __restrict__ A1,
                                                float* __restrict__ xa2) {
  int bid = blockIdx.x; int b = bid >> 5, q = bid & 31;   // q: 128-col chunk of 4096
  __shared__ float At[64*68];                              // A1 transposed [j][c]
  __shared__ __align__(16) float Hs[64*132];
  int t = threadIdx.x;
#pragma unroll
  for (int p = 0; p < 16; ++p) {
    int m = t + p*256;                      // A1[c*64+j]
    At[(m & 63)*68 + (m >> 6)] = A1[m];
  }
  const float* hb = h + ((size_t)b*64)*4096 + q*128;
#pragma unroll
  for (int p = 0; p < 8; ++p) {
    int idx = t + p*256;                    // 2048 float4 tiles: 64 j x 32 f4
    int j = idx >> 5, f4 = idx & 31;
    *(float4*)&Hs[j*132 + f4*4] = *(const float4*)(hb + (size_t)j*4096 + f4*4);
  }
  __syncthreads();
  int tx = t & 31, ty = t >> 5;             // tx: f4 col, ty: 8-row c block
  float acc[8][4] = {};
  for (int j = 0; j < 64; ++j) {
    float a[8];
    *(float4*)&a[0] = *(const float4*)&At[j*68 + ty*8];
    *(float4*)&a[4] = *(const float4*)&At[j*68 + ty*8 + 4];
    float4 hv = *(const float4*)&Hs[j*132 + tx*4];
#pragma unroll
    for (int i = 0; i < 8; ++i) {
      acc[i][0] = fmaf(a[i], hv.x, acc[i][0]);
      acc[i][1] = fmaf(a[i], hv.y, acc[i][1]);
      acc[i][2] = fmaf(a[i], hv.z, acc[i][2]);
      acc[i][3] = fmaf(a[i], hv.w, acc[i][3]);
    }
  }
  float* outp = xa2 + (((size_t)b*64) << 12) + q*128 + tx*4;
#pragma unroll
  for (int i = 0; i < 8; ++i) {
    int c = ty*8 + i;
    *(float4*)(outp + ((size_t)c << 12)) =
        make_float4(acc[i][0], acc[i][1], acc[i][2], acc[i][3]);
  }
}

// ---- gemm1e: y1 = prelu(bn(xa @ W1 + b1)); full pool1 row-dot -----------------------
// block: 256 thr, BM=64 rows (2 c x 32 tp), BN=256 (all cols), 8x8 microtile.
// grid 1024 = 4 blocks/CU = 16 waves/CU (round-4 validated occupancy shape).
__global__ __launch_bounds__(256) void gemm1e(const float* __restrict__ xa2,
                                              const float* __restrict__ W1,
                                              const float* __restrict__ gc1b,
                                              const float* __restrict__ g1,
                                              const float* __restrict__ be1,
                                              const float* __restrict__ mu1,
                                              const float* __restrict__ v1,
                                              const float* __restrict__ pa1,
                                              const float* __restrict__ pw1,
                                              float* __restrict__ y1,
                                              float* __restrict__ dots1) {
  __shared__ __align__(16) float As[16*68];    // [k][row], row = cl*32+tp
  __shared__ __align__(16) float Bs[16*260];   // [k][col 0..255]
  int t = threadIdx.x;
  int mb = blockIdx.x; int b = mb >> 5, c0 = (mb & 31) * 2;
  int tx = t & 31, ty = t >> 5;                // tx: col group, ty: row group
  float acc[8][8] = {};
  const float* abase = xa2 + (((size_t)(b*64 + c0)) << 12);
  for (int k0 = 0; k0 < 128; k0 += 16) {
    {                                          // A tile: 256 f4, one per thread
      int kl = t >> 4, rr4 = t & 15;
      int cl = rr4 >> 3, tp0 = (rr4 & 7)*4;
      float4 av = *(const float4*)(abase + ((size_t)cl << 12) + (k0 + kl)*32 + tp0);
      *(float4*)&As[kl*68 + cl*32 + tp0] = av;
    }
#pragma unroll
    for (int p = 0; p < 4; ++p) {              // B tile: 1024 f4: 16 k x 64 col4
      int idx = t + p*256;
      int rk = idx >> 6, cn = (idx & 63)*4;
      *(float4*)&Bs[rk*260 + cn] = *(const float4*)(W1 + (size_t)(k0+rk)*NHID + cn);
    }
    __syncthreads();
#pragma unroll
    for (int kk = 0; kk < 16; ++kk) {
      float a[8], bb[8];
      *(float4*)&a[0]  = *(const float4*)&As[kk*68 + 4*ty];
      *(float4*)&a[4]  = *(const float4*)&As[kk*68 + 32 + 4*ty];
      *(float4*)&bb[0] = *(const float4*)&Bs[kk*260 + 4*tx];
      *(float4*)&bb[4] = *(const float4*)&Bs[kk*260 + 128 + 4*tx];
#pragma unroll
      for (int i = 0; i < 8; ++i)
#pragma unroll
        for (int j = 0; j < 8; ++j)
          acc[i][j] = fmaf(a[i], bb[j], acc[i][j]);
    }
    __syncthreads();
  }
  // epilogue constants (late, to keep loop VGPR pressure low)
  float4 scv[2], shv[2], pwv[2];
#pragma unroll
  for (int jh = 0; jh < 2; ++jh) {
    int col = jh*128 + 4*tx;
    float4 gv = *(const float4*)(g1 + col);
    float4 vv = *(const float4*)(v1 + col);
    float4 bv = *(const float4*)(be1 + col);
    float4 mv = *(const float4*)(mu1 + col);
    float4 b0 = *(const float4*)(gc1b + col);
    float4 s;
    s.x = gv.x * rsqrtf(vv.x + 1e-5f); s.y = gv.y * rsqrtf(vv.y + 1e-5f);
    s.z = gv.z * rsqrtf(vv.z + 1e-5f); s.w = gv.w * rsqrtf(vv.w + 1e-5f);
    scv[jh] = s;
    shv[jh] = make_float4((b0.x - mv.x)*s.x + bv.x, (b0.y - mv.y)*s.y + bv.y,
                          (b0.z - mv.z)*s.z + bv.z, (b0.w - mv.w)*s.w + bv.w);
    pwv[jh] = *(const float4*)(pw1 + col);
  }
  float a1v = pa1[0];
#pragma unroll
  for (int ih = 0; ih < 2; ++ih)
#pragma unroll
    for (int i = 0; i < 4; ++i) {
      int cl = ih, tp = 4*ty + i;
      size_t R = (size_t)(b*32 + tp)*64 + c0 + cl;
      float dpart = 0.f;
#pragma unroll
      for (int jh = 0; jh < 2; ++jh) {
        float4 o;
        o.x = acc[ih*4+i][jh*4+0]*scv[jh].x + shv[jh].x;
        o.y = acc[ih*4+i][jh*4+1]*scv[jh].y + shv[jh].y;
        o.z = acc[ih*4+i][jh*4+2]*scv[jh].z + shv[jh].z;
        o.w = acc[ih*4+i][jh*4+3]*scv[jh].w + shv[jh].w;
        o.x = o.x >= 0.f ? o.x : a1v*o.x; o.y = o.y >= 0.f ? o.y : a1v*o.y;
        o.z = o.z >= 0.f ? o.z : a1v*o.z; o.w = o.w >= 0.f ? o.w : a1v*o.w;
        *(float4*)(y1 + R*NHID + jh*128 + 4*tx) = o;
        dpart += o.x*pwv[jh].x + o.y*pwv[jh].y + o.z*pwv[jh].z + o.w*pwv[jh].w;
      }
      dpart += __shfl_xor(dpart, 1);
      dpart += __shfl_xor(dpart, 2);
      dpart += __shfl_xor(dpart, 4);
      dpart += __shfl_xor(dpart, 8);
      dpart += __shfl_xor(dpart, 16);
      if (tx == 0) dots1[R] = dpart;
    }
}

// ---- pool1s: scores = As1 @ dots + b; stable top-52; emit rowsrc/rowgate/nidx -------
__global__ __launch_bounds__(256) void pool1s(const float* __restrict__ dots1,
                                              const float* __restrict__ As1,
                                              const float* __restrict__ p1b,
                                              int* __restrict__ rowsrc,
                                              float* __restrict__ rowgate,
                                              int* __restrict__ nidx) {
  int g = blockIdx.x, t = threadIdx.x;
  __shared__ float As1s[64*65];
  __shared__ float sp[64], s[64];
  __shared__ int perm[K1_];
  __shared__ float gate[K1_];
  for (int i = t; i < 4096; i += 256)
    As1s[(i >> 6)*65 + (i & 63)] = As1[i];
  if (t < 64) sp[t] = dots1[g*64 + t];
  __syncthreads();
  if (t < 64) {
    float acc = p1b[0];
    for (int j = 0; j < 64; ++j) acc = fmaf(As1s[t*65 + j], sp[j], acc);
    s[t] = acc;
  }
  __syncthreads();
  if (t < 64) {
    float si = s[t];
    int rank = 0;
    for (int j = 0; j < 64; ++j) {
      float sj = s[j];
      rank += (sj > si) || (sj == si && j < t);
    }
    nidx[g*64 + t] = (rank < K1_) ? rank : -1;
    if (rank < K1_) { perm[rank] = t; gate[rank] = tanhf(si); }
  }
  __syncthreads();
  if (t < K1_) {
    rowsrc[g*K1_ + t]  = g*64 + perm[t];
    rowgate[g*K1_ + t] = gate[t];
  }
}

// ---- gemm2g: xw2 = (gathered, gated y1) @ W2; 8x8 microtile, BM=128, BN=128 ---------
__global__ __launch_bounds__(256) void gemm2g(const float* __restrict__ y1,
                                              const int* __restrict__ rowsrc,
                                              const float* __restrict__ rowgate,
                                              const float* __restrict__ W2,
                                              float* __restrict__ xw2) {
  __shared__ __align__(16) float As[16][132];
  __shared__ __align__(16) float Bs[16][132];
  int t = threadIdx.x;
  int row0 = blockIdx.x * 128;
  int tx = t & 15, ty = t >> 4;
  float acc[8][8] = {};
  for (int k0 = 0; k0 < NHID; k0 += 16) {
#pragma unroll
    for (int p = 0; p < 2; ++p) {
      int rm = (t >> 2) + p*64, tq = t & 3;
      int sr = rowsrc[row0 + rm];
      float gt = rowgate[row0 + rm];
      float4 av = *(const float4*)(y1 + (size_t)sr * NHID + k0 + 4*tq);
      As[4*tq+0][rm] = av.x * gt; As[4*tq+1][rm] = av.y * gt;
      As[4*tq+2][rm] = av.z * gt; As[4*tq+3][rm] = av.w * gt;
    }
#pragma unroll
    for (int p = 0; p < 2; ++p) {
      int rk = (t >> 5) + p*8, cn = (t & 31)*4;
      *(float4*)&Bs[rk][cn] = *(const float4*)(W2 + (size_t)(k0 + rk)*NOUT + cn);
    }
    __syncthreads();
#pragma unroll
    for (int kk = 0; kk < 16; ++kk) {
      float a[8], b[8];
      *(float4*)&a[0] = *(const float4*)&As[kk][4*ty];
      *(float4*)&a[4] = *(const float4*)&As[kk][64 + 4*ty];
      *(float4*)&b[0] = *(const float4*)&Bs[kk][4*tx];
      *(float4*)&b[4] = *(const float4*)&Bs[kk][64 + 4*tx];
#pragma unroll
      for (int i = 0; i < 8; ++i)
#pragma unroll
        for (int j = 0; j < 8; ++j)
          acc[i][j] = fmaf(a[i], b[j], acc[i][j]);
    }
    __syncthreads();
  }
#pragma unroll
  for (int ih = 0; ih < 2; ++ih)
#pragma unroll
    for (int i = 0; i < 4; ++i) {
      int r = row0 + ih*64 + 4*ty + i;
#pragma unroll
      for (int jh = 0; jh < 2; ++jh) {
        float4 v = make_float4(acc[ih*4+i][jh*4+0], acc[ih*4+i][jh*4+1],
                               acc[ih*4+i][jh*4+2], acc[ih*4+i][jh*4+3]);
        *(float4*)(xw2 + (size_t)r * NOUT + jh*64 + 4*tx) = v;
      }
    }
}

// ---- mega2r: build A2/As2 + agg+BN+PReLU (y2 in regs) + dots + scores + rank-out ----
__global__ __launch_bounds__(256) void mega2r(const int* __restrict__ ei,
                                              const float* __restrict__ ew,
                                              const int* __restrict__ nidx,
                                              const float* __restrict__ xw2,
                                              const float* __restrict__ gc2b,
                                              const float* __restrict__ g2,
                                              const float* __restrict__ be2,
                                              const float* __restrict__ mu2,
                                              const float* __restrict__ v2,
                                              const float* __restrict__ pa2,
                                              const float* __restrict__ pw2,
                                              const float* __restrict__ p2b,
                                              float* __restrict__ out) {
  int g = blockIdx.x, t = threadIdx.x;
  __shared__ float A2t[64*68];                 // [j][c] zero-padded
  __shared__ float As2s[K1_*K1_];
  __shared__ __align__(16) float xs[K1_*132];
  __shared__ float dg[K1_], dgs[K1_], dis[K1_], diss[K1_], d[K1_], s[K1_], gA[K1_];
  __shared__ int nm[C_], rankA[K1_];
  __shared__ float4 zpart[8][32];

  for (int i = t; i < 64*68; i += 256) A2t[i] = 0.f;
  for (int i = t; i < K1_*K1_; i += 256) As2s[i] = 0.f;
  if (t < C_) nm[t] = nidx[g*C_ + t];
  if (t < K1_) { dg[t] = 1.f; dgs[t] = 1.f; }
  for (int p = 0; p < 7; ++p) {
    int idx = t + p*256;
    if (idx < K1_*32) {
      int r = idx >> 5, f4 = idx & 31;
      *(float4*)&xs[r*132 + f4*4] =
          *(const float4*)(xw2 + ((size_t)g*K1_ + r)*NOUT + f4*4);
    }
  }
  int eR[2], eC[2]; float eW[2];
#pragma unroll
  for (int p = 0; p < 2; ++p) {
    int e = t + p*256;
    eR[p] = ei[e]; eC[p] = ei[E_ + e]; eW[p] = ew[e];
  }
  __syncthreads();
  int nr[2], nc[2]; bool val[2];
#pragma unroll
  for (int p = 0; p < 2; ++p) {
    nr[p] = nm[eR[p]]; nc[p] = nm[eC[p]];
    val[p] = (nr[p] >= 0) && (nc[p] >= 0);
    if (val[p]) { atomicAdd(&dg[nc[p]], eW[p]); atomicAdd(&dgs[nc[p]], 1.f); }
  }
  __syncthreads();
  if (t < K1_) { dis[t] = rsqrtf(dg[t]); diss[t] = rsqrtf(dgs[t]); }
  __syncthreads();
#pragma unroll
  for (int p = 0; p < 2; ++p) {
    if (val[p]) {
      atomicAdd(&A2t[nr[p]*68 + nc[p]],  dis[nr[p]] * eW[p] * dis[nc[p]]);
      atomicAdd(&As2s[nc[p]*K1_ + nr[p]], diss[nr[p]] * diss[nc[p]]);
    }
  }
  if (t < K1_) {
    atomicAdd(&A2t[t*68 + t],   dis[t]*dis[t]);
    atomicAdd(&As2s[t*K1_ + t], diss[t]*diss[t]);
  }
  __syncthreads();
  // agg: rows c = ty*8+i, cols 4*tx
  int tx = t & 31, ty = t >> 5;
  float4 scv, shv, pwv;
  {
    int col = 4*tx;
    float4 gv = *(const float4*)(g2 + col);
    float4 vv = *(const float4*)(v2 + col);
    float4 bv = *(const float4*)(be2 + col);
    float4 mv = *(const float4*)(mu2 + col);
    float4 b0 = *(const float4*)(gc2b + col);
    scv.x = gv.x * rsqrtf(vv.x + 1e-5f); scv.y = gv.y * rsqrtf(vv.y + 1e-5f);
    scv.z = gv.z * rsqrtf(vv.z + 1e-5f); scv.w = gv.w * rsqrtf(vv.w + 1e-5f);
    shv = make_float4((b0.x - mv.x)*scv.x + bv.x, (b0.y - mv.y)*scv.y + bv.y,
                      (b0.z - mv.z)*scv.z + bv.z, (b0.w - mv.w)*scv.w + bv.w);
    pwv = *(const float4*)(pw2 + col);
  }
  float a2v = pa2[0];
  float acc[8][4] = {};
  for (int j = 0; j < K1_; ++j) {
    float a[8];
    *(float4*)&a[0] = *(const float4*)&A2t[j*68 + ty*8];
    *(float4*)&a[4] = *(const float4*)&A2t[j*68 + ty*8 + 4];
    float4 xv = *(const float4*)&xs[j*132 + tx*4];
#pragma unroll
    for (int i = 0; i < 8; ++i) {
      acc[i][0] = fmaf(a[i], xv.x, acc[i][0]);
      acc[i][1] = fmaf(a[i], xv.y, acc[i][1]);
      acc[i][2] = fmaf(a[i], xv.z, acc[i][2]);
      acc[i][3] = fmaf(a[i], xv.w, acc[i][3]);
    }
  }
  // BN + PReLU in registers (y2 never leaves the block); node dots
#pragma unroll
  for (int i = 0; i < 8; ++i) {
    int c = ty*8 + i;
    if (c < K1_) {
      float4 o;
      o.x = acc[i][0]*scv.x + shv.x; o.y = acc[i][1]*scv.y + shv.y;
      o.z = acc[i][2]*scv.z + shv.z; o.w = acc[i][3]*scv.w + shv.w;
      o.x = o.x >= 0.f ? o.x : a2v*o.x; o.y = o.y >= 0.f ? o.y : a2v*o.y;
      o.z = o.z >= 0.f ? o.z : a2v*o.z; o.w = o.w >= 0.f ? o.w : a2v*o.w;
      acc[i][0] = o.x; acc[i][1] = o.y; acc[i][2] = o.z; acc[i][3] = o.w;
      float dp = o.x*pwv.x + o.y*pwv.y + o.z*pwv.z + o.w*pwv.w;
      dp += __shfl_xor(dp, 1);
      dp += __shfl_xor(dp, 2);
      dp += __shfl_xor(dp, 4);
      dp += __shfl_xor(dp, 8);
      dp += __shfl_xor(dp, 16);
      if (tx == 0) d[c] = dp;
    }
  }
  __syncthreads();
  if (t < K1_) {
    float sv = p2b[0];
    for (int j = 0; j < K1_; ++j) sv = fmaf(As2s[t*K1_ + j], d[j], sv);
    s[t] = sv;
  }
  __syncthreads();
  if (t < K1_) {
    float si = s[t];
    int rank = 0;
    for (int j = 0; j < K1_; ++j) {
      float sj = s[j];
      rank += (sj > si) || (sj == si && j < t);
    }
    rankA[t] = rank;
    gA[t] = tanhf(si);
  }
  __syncthreads();
  // rank-directed output: row c -> slot rankA[c] if selected
  float4 zp = make_float4(0.f, 0.f, 0.f, 0.f);
#pragma unroll
  for (int i = 0; i < 8; ++i) {
    int c = ty*8 + i;
    if (c < K1_) {
      int r = rankA[c];
      if (r < K2_) {
        float gt = gA[c];
        float4 v = make_float4(acc[i][0]*gt, acc[i][1]*gt, acc[i][2]*gt, acc[i][3]*gt);
        *(float4*)(out + ((size_t)g*K2_ + r)*NOUT + 4*tx) = v;
        zp.x += v.x; zp.y += v.y; zp.z += v.z; zp.w += v.w;
      }
    }
  }
  zpart[ty][tx] = zp;
  __syncthreads();
  if (t < 32) {
    float4 z = make_float4(0.f, 0.f, 0.f, 0.f);
#pragma unroll
    for (int k = 0; k < 8; ++k) {
      float4 v = zpart[k][t];
      z.x += v.x; z.y += v.y; z.z += v.z; z.w += v.w;
    }
    const float inv = 1.0f / (float)K2_;
    z.x *= inv; z.y *= inv; z.z *= inv; z.w *= inv;
    *(float4*)(out + (size_t)G_*K2_*NOUT + (size_t)g*NOUT + 4*t) = z;
  }
}

extern "C" void kernel_launch(void* const* d_in, const int* in_sizes, int n_in,
                              void* d_out, int out_size, void* d_ws, size_t ws_size,
                              hipStream_t stream) {
  const float* h    = (const float*)d_in[0];
  const int*   ei   = (const int*)  d_in[1];
  const float* ew   = (const float*)d_in[2];
  const float* gc1w = (const float*)d_in[3];
  const float* gc1b = (const float*)d_in[4];
  const float* bn1g = (const float*)d_in[5];
  const float* bn1b = (const float*)d_in[6];
  const float* bn1m = (const float*)d_in[7];
  const float* bn1v = (const float*)d_in[8];
  const float* pr1a = (const float*)d_in[9];
  const float* p1w  = (const float*)d_in[10];
  const float* p1b  = (const float*)d_in[11];
  const float* gc2w = (const float*)d_in[12];
  const float* gc2b = (const float*)d_in[13];
  const float* bn2g = (const float*)d_in[14];
  const float* bn2b = (const float*)d_in[15];
  const float* bn2m = (const float*)d_in[16];
  const float* bn2v = (const float*)d_in[17];
  const float* pr2a = (const float*)d_in[18];
  const float* p2w  = (const float*)d_in[19];
  const float* p2b  = (const float*)d_in[20];

  float* w = (float*)d_ws;
  // float offsets
  float* A1      = w;                       // 4096
  float* As1     = w + 4096;                // 4096
  float* dots1   = w + 8192;                // 65536
  int*   nidx    = (int*)(w + 139264);      // 65536
  int*   rowsrc  = (int*)(w + 204800);      // 53248
  float* rowgate = w + 258048;              // 53248
  float* xa2     = w + 327680;              // 8388608  (32*64*128*32)
  float* y1      = w + 8716288;             // 16777216 (65536*256)  end 25493504 fl
  float* xw2     = xa2;                     // 6815744 <= 8388608 (xa2 dead after gemm1e)

  build_A1<<<1, 256, 0, stream>>>(ei, ew, A1, As1);
  preagg_b<<<1024, 256, 0, stream>>>(h, A1, xa2);
  gemm1e<<<1024, 256, 0, stream>>>(xa2, gc1w, gc1b, bn1g, bn1b, bn1m, bn1v,
                                   pr1a, p1w, y1, dots1);
  pool1s<<<G_, 256, 0, stream>>>(dots1, As1, p1b, rowsrc, rowgate, nidx);
  gemm2g<<<416, 256, 0, stream>>>(y1, rowsrc, rowgate, gc2w, xw2);
  mega2r<<<G_, 256, 0, stream>>>(ei, ew, nidx, xw2, gc2b, bn2g, bn2b, bn2m, bn2v,
                                 pr2a, p2w, p2b, (float*)d_out);
}

// Round 8
// 165.539 us; speedup vs baseline: 1.9984x; 1.0965x over previous
//
#include <hip/hip_runtime.h>
#include <math.h>

#define B_   32
#define C_   64
#define F_   128
#define TP_  32
#define G_   (B_*TP_)      // 1024 graphs
#define NHID 256
#define NOUT 128
#define E_   512
#define K1_  52            // ceil(0.8*64)
#define K2_  42            // ceil(0.8*52)
#define N2_  (G_*K1_)      // 53248 rows layer 2

typedef __attribute__((ext_vector_type(8))) short short8_t;   // 8 bf16 (4 VGPR)
typedef __attribute__((ext_vector_type(4))) float f32x4_t;

__device__ __forceinline__ void split_bf16(float v, unsigned short &h, unsigned short &l) {
  unsigned u = __float_as_uint(v);
  unsigned hb = (u + 0x7FFFu + ((u >> 16) & 1u)) & 0xFFFF0000u;  // RNE bf16 of v
  float hf = __uint_as_float(hb);
  float r = v - hf;                                              // exact in f32
  unsigned ur = __float_as_uint(r);
  unsigned lb = (ur + 0x7FFFu + ((ur >> 16) & 1u)) >> 16;        // RNE bf16 of r
  h = (unsigned short)(hb >> 16);
  l = (unsigned short)lb;
}

// -------- build shared 64x64 A1 (edge-weight norm) and As1 (binary norm) -------------
__global__ __launch_bounds__(256) void build_A1(const int* __restrict__ ei,
                                                const float* __restrict__ ew,
                                                float* __restrict__ A1,
                                                float* __restrict__ As1) {
  __shared__ float A1s[C_*C_], As1s[C_*C_];
  __shared__ float dg[C_], dgs[C_], dis[C_], diss[C_];
  int t = threadIdx.x;
  for (int i = t; i < C_*C_; i += 256) { A1s[i] = 0.f; As1s[i] = 0.f; }
  if (t < C_) { dg[t] = 1.f; dgs[t] = 1.f; }   // self-loop weight 1
  int r0[2], c0[2]; float w0[2];
#pragma unroll
  for (int p = 0; p < 2; ++p) {
    int e = t + p*256;
    r0[p] = ei[e]; c0[p] = ei[E_ + e]; w0[p] = ew[e];
  }
  __syncthreads();
#pragma unroll
  for (int p = 0; p < 2; ++p) {
    atomicAdd(&dg[c0[p]], w0[p]);
    atomicAdd(&dgs[c0[p]], 1.f);
  }
  __syncthreads();
  if (t < C_) { dis[t] = rsqrtf(dg[t]); diss[t] = rsqrtf(dgs[t]); }
  __syncthreads();
#pragma unroll
  for (int p = 0; p < 2; ++p) {
    int r = r0[p], c = c0[p];
    atomicAdd(&A1s[c*C_ + r],  dis[r] * w0[p] * dis[c]);
    atomicAdd(&As1s[c*C_ + r], diss[r] * diss[c]);
  }
  if (t < C_) {
    atomicAdd(&A1s[t*C_ + t],  dis[t] * dis[t]);
    atomicAdd(&As1s[t*C_ + t], diss[t] * diss[t]);
  }
  __syncthreads();
  for (int i = t; i < C_*C_; i += 256) { A1[i] = A1s[i]; As1[i] = As1s[i]; }
}

// ---- w1prep: W1 [k 128][col 256] f32 -> W1t hi/lo [col][k] bf16 ----------------------
__global__ __launch_bounds__(256) void w1prep(const float* __restrict__ W1,
                                              unsigned short* __restrict__ Whi,
                                              unsigned short* __restrict__ Wlo) {
  int tid = blockIdx.x*256 + threadIdx.x;     // 16384 threads, 2 k's each
  int col = tid >> 6, k2 = tid & 63;
  float v0 = W1[(size_t)(2*k2)*NHID + col];
  float v1 = W1[(size_t)(2*k2+1)*NHID + col];
  unsigned short h0,l0,h1,l1;
  split_bf16(v0, h0, l0);
  split_bf16(v1, h1, l1);
  *(unsigned*)&Whi[(size_t)col*128 + 2*k2] = (unsigned)h0 | ((unsigned)h1 << 16);
  *(unsigned*)&Wlo[(size_t)col*128 + 2*k2] = (unsigned)l0 | ((unsigned)l1 << 16);
}

// ---- preagg: xa2[b,c,f,tp] = sum_j A1[c,j] * h[b,j,f,tp]  (per-b, (f,tp) cols) ------
__global__ __launch_bounds__(256) void preagg_b(const float* __restrict__ h,
                                                const float* __restrict__ A1,
                                                float* __restrict__ xa2) {
  int bid = blockIdx.x; int b = bid >> 5, q = bid & 31;   // q: 128-col chunk of 4096
  __shared__ float At[64*68];                              // A1 transposed [j][c]
  __shared__ __align__(16) float Hs[64*132];
  int t = threadIdx.x;
#pragma unroll
  for (int p = 0; p < 16; ++p) {
    int m = t + p*256;                      // A1[c*64+j]
    At[(m & 63)*68 + (m >> 6)] = A1[m];
  }
  const float* hb = h + ((size_t)b*64)*4096 + q*128;
#pragma unroll
  for (int p = 0; p < 8; ++p) {
    int idx = t + p*256;                    // 2048 float4 tiles: 64 j x 32 f4
    int j = idx >> 5, f4 = idx & 31;
    *(float4*)&Hs[j*132 + f4*4] = *(const float4*)(hb + (size_t)j*4096 + f4*4);
  }
  __syncthreads();
  int tx = t & 31, ty = t >> 5;             // tx: f4 col, ty: 8-row c block
  float acc[8][4] = {};
  for (int j = 0; j < 64; ++j) {
    float a[8];
    *(float4*)&a[0] = *(const float4*)&At[j*68 + ty*8];
    *(float4*)&a[4] = *(const float4*)&At[j*68 + ty*8 + 4];
    float4 hv = *(const float4*)&Hs[j*132 + tx*4];
#pragma unroll
    for (int i = 0; i < 8; ++i) {
      acc[i][0] = fmaf(a[i], hv.x, acc[i][0]);
      acc[i][1] = fmaf(a[i], hv.y, acc[i][1]);
      acc[i][2] = fmaf(a[i], hv.z, acc[i][2]);
      acc[i][3] = fmaf(a[i], hv.w, acc[i][3]);
    }
  }
  float* outp = xa2 + (((size_t)b*64) << 12) + q*128 + tx*4;
#pragma unroll
  for (int i = 0; i < 8; ++i) {
    int c = ty*8 + i;
    *(float4*)(outp + ((size_t)c << 12)) =
        make_float4(acc[i][0], acc[i][1], acc[i][2], acc[i][3]);
  }
}

// ---- xa_cvt: xa2 [b][c][f][tp] f32 -> xahi/xalo [R][k=f] bf16, R=(b*32+tp)*64+c -----
__global__ __launch_bounds__(256) void xa_cvt(const float* __restrict__ xa2,
                                              unsigned short* __restrict__ xahi,
                                              unsigned short* __restrict__ xalo) {
  int bid = blockIdx.x;                      // 1024: b = bid>>5, cpair
  int b = bid >> 5, c0 = (bid & 31) * 2;
  __shared__ float xs[8192];                 // [c_l 2][f 128][tp 32]
  int t = threadIdx.x;
  const float* src = xa2 + ((size_t)(b*64 + c0) << 12);
#pragma unroll
  for (int p = 0; p < 8; ++p) {
    int idx = (t + p*256) * 4;
    *(float4*)&xs[idx] = *(const float4*)(src + idx);
  }
  __syncthreads();
  int row_l = t >> 2, fq = t & 3;            // row_l = c_l*32+tp
  int c_l = row_l >> 5, tp = row_l & 31;
  size_t R = ((size_t)b*32 + tp)*64 + c0 + c_l;
  const float* base = &xs[c_l*4096 + tp];
#pragma unroll
  for (int i = 0; i < 4; ++i) {
    int f8 = fq + 4*i;
    unsigned hp[4], lp[4];
#pragma unroll
    for (int jj = 0; jj < 4; ++jj) {
      unsigned short h0,l0,h1,l1;
      split_bf16(base[(f8*8 + 2*jj    )*32], h0, l0);
      split_bf16(base[(f8*8 + 2*jj + 1)*32], h1, l1);
      hp[jj] = (unsigned)h0 | ((unsigned)h1 << 16);
      lp[jj] = (unsigned)l0 | ((unsigned)l1 << 16);
    }
    *(uint4*)&xahi[R*128 + f8*8] = make_uint4(hp[0], hp[1], hp[2], hp[3]);
    *(uint4*)&xalo[R*128 + f8*8] = make_uint4(lp[0], lp[1], lp[2], lp[3]);
  }
}

// ---- gemm1m: y1 = prelu(bn(xa @ W1 + b1)) via bf16x3 MFMA; partial pool1 dots -------
// block: 64 rows x 128 cols (colhalf), 4 waves; wave = 64 rows x 32 cols (4x2 tiles)
__global__ __launch_bounds__(256) void gemm1m(const unsigned short* __restrict__ xahi,
                                              const unsigned short* __restrict__ xalo,
                                              const unsigned short* __restrict__ Whi,
                                              const unsigned short* __restrict__ Wlo,
                                              const float* __restrict__ gc1b,
                                              const float* __restrict__ g1,
                                              const float* __restrict__ be1,
                                              const float* __restrict__ mu1,
                                              const float* __restrict__ v1,
                                              const float* __restrict__ pa1,
                                              const float* __restrict__ pw1,
                                              float* __restrict__ y1,
                                              float* __restrict__ dots2) {
  __shared__ unsigned short Ahs[64*40], Als[64*40];     // [row][k32 pad40]
  __shared__ unsigned short Bhs[128*40], Bls[128*40];   // [col][k32 pad40]
  __shared__ float dsum[64*4];
  int t = threadIdx.x;
  int row0 = blockIdx.x * 64;
  int colhalf = blockIdx.y;
  int w = t >> 6, l = t & 63, lr = l & 15, lg = l >> 4;
  f32x4_t acc[4][2] = {};
  for (int k0 = 0; k0 < 128; k0 += 32) {
    {   // stage A: 64 rows x 32 k, 16B chunk per thread per plane
      int row = t >> 2, kq = t & 3;
      size_t src = (size_t)(row0 + row)*128 + k0 + kq*8;
      *(uint4*)&Ahs[row*40 + kq*8] = *(const uint4*)&xahi[src];
      *(uint4*)&Als[row*40 + kq*8] = *(const uint4*)&xalo[src];
    }
#pragma unroll
    for (int p = 0; p < 2; ++p) {   // stage B: 128 cols x 32 k
      int id = t + p*256;
      int colb = id >> 2, kq = id & 3;
      size_t src = (size_t)(colhalf*128 + colb)*128 + k0 + kq*8;
      *(uint4*)&Bhs[colb*40 + kq*8] = *(const uint4*)&Whi[src];
      *(uint4*)&Bls[colb*40 + kq*8] = *(const uint4*)&Wlo[src];
    }
    __syncthreads();
    short8_t ah[4], al[4], bh[2], bl[2];
#pragma unroll
    for (int s = 0; s < 4; ++s) {
      int off = (s*16 + lr)*40 + lg*8;
      ah[s] = *(const short8_t*)&Ahs[off];
      al[s] = *(const short8_t*)&Als[off];
    }
#pragma unroll
    for (int t2 = 0; t2 < 2; ++t2) {
      int off = (w*32 + t2*16 + lr)*40 + lg*8;
      bh[t2] = *(const short8_t*)&Bhs[off];
      bl[t2] = *(const short8_t*)&Bls[off];
    }
#pragma unroll
    for (int s = 0; s < 4; ++s)
#pragma unroll
      for (int t2 = 0; t2 < 2; ++t2) {
        acc[s][t2] = __builtin_amdgcn_mfma_f32_16x16x32_bf16(ah[s], bh[t2], acc[s][t2], 0, 0, 0);
        acc[s][t2] = __builtin_amdgcn_mfma_f32_16x16x32_bf16(al[s], bh[t2], acc[s][t2], 0, 0, 0);
        acc[s][t2] = __builtin_amdgcn_mfma_f32_16x16x32_bf16(ah[s], bl[t2], acc[s][t2], 0, 0, 0);
      }
    __syncthreads();
  }
  // epilogue: BN + PReLU + y1 write + pool dot partials
  float sc_[2], sh_[2], pw_[2];
#pragma unroll
  for (int t2 = 0; t2 < 2; ++t2) {
    int col_g = colhalf*128 + w*32 + t2*16 + lr;
    float s = g1[col_g] * rsqrtf(v1[col_g] + 1e-5f);
    sc_[t2] = s;
    sh_[t2] = (gc1b[col_g] - mu1[col_g])*s + be1[col_g];
    pw_[t2] = pw1[col_g];
  }
  float a1v = pa1[0];
#pragma unroll
  for (int s = 0; s < 4; ++s)
#pragma unroll
    for (int j = 0; j < 4; ++j) {
      int row_l = s*16 + lg*4 + j;
      size_t R = (size_t)row0 + row_l;
      float d = 0.f;
#pragma unroll
      for (int t2 = 0; t2 < 2; ++t2) {
        float o = acc[s][t2][j]*sc_[t2] + sh_[t2];
        o = o >= 0.f ? o : a1v*o;
        y1[R*NHID + colhalf*128 + w*32 + t2*16 + lr] = o;
        d += o * pw_[t2];
      }
      d += __shfl_xor(d, 1);
      d += __shfl_xor(d, 2);
      d += __shfl_xor(d, 4);
      d += __shfl_xor(d, 8);
      if (lr == 0) dsum[row_l*4 + w] = d;
    }
  __syncthreads();
  if (t < 64)
    dots2[((size_t)row0 + t)*2 + colhalf] =
        (dsum[t*4+0] + dsum[t*4+1]) + (dsum[t*4+2] + dsum[t*4+3]);
}

// ---- pool1s: scores = As1 @ dots + b; stable top-52; emit rowsrc/rowgate/nidx -------
__global__ __launch_bounds__(256) void pool1s(const float* __restrict__ dots2,
                                              const float* __restrict__ As1,
                                              const float* __restrict__ p1b,
                                              int* __restrict__ rowsrc,
                                              float* __restrict__ rowgate,
                                              int* __restrict__ nidx) {
  int g = blockIdx.x, t = threadIdx.x;
  __shared__ float As1s[64*65];
  __shared__ float sp[64], s[64];
  __shared__ int perm[K1_];
  __shared__ float gate[K1_];
  for (int i = t; i < 4096; i += 256)
    As1s[(i >> 6)*65 + (i & 63)] = As1[i];
  if (t < 64) sp[t] = dots2[(g*64 + t)*2] + dots2[(g*64 + t)*2 + 1];
  __syncthreads();
  if (t < 64) {
    float acc = p1b[0];
    for (int j = 0; j < 64; ++j) acc = fmaf(As1s[t*65 + j], sp[j], acc);
    s[t] = acc;
  }
  __syncthreads();
  if (t < 64) {
    float si = s[t];
    int rank = 0;
    for (int j = 0; j < 64; ++j) {
      float sj = s[j];
      rank += (sj > si) || (sj == si && j < t);
    }
    nidx[g*64 + t] = (rank < K1_) ? rank : -1;
    if (rank < K1_) { perm[rank] = t; gate[rank] = tanhf(si); }
  }
  __syncthreads();
  if (t < K1_) {
    rowsrc[g*K1_ + t]  = g*64 + perm[t];
    rowgate[g*K1_ + t] = gate[t];
  }
}

// ---- gemm2g: xw2 = (gathered, gated y1) @ W2; 8x8 microtile, BM=128, BN=128 ---------
__global__ __launch_bounds__(256) void gemm2g(const float* __restrict__ y1,
                                              const int* __restrict__ rowsrc,
                                              const float* __restrict__ rowgate,
                                              const float* __restrict__ W2,
                                              float* __restrict__ xw2) {
  __shared__ __align__(16) float As[16][132];
  __shared__ __align__(16) float Bs[16][132];
  int t = threadIdx.x;
  int row0 = blockIdx.x * 128;
  int tx = t & 15, ty = t >> 4;
  float acc[8][8] = {};
  for (int k0 = 0; k0 < NHID; k0 += 16) {
#pragma unroll
    for (int p = 0; p < 2; ++p) {
      int rm = (t >> 2) + p*64, tq = t & 3;
      int sr = rowsrc[row0 + rm];
      float gt = rowgate[row0 + rm];
      float4 av = *(const float4*)(y1 + (size_t)sr * NHID + k0 + 4*tq);
      As[4*tq+0][rm] = av.x * gt; As[4*tq+1][rm] = av.y * gt;
      As[4*tq+2][rm] = av.z * gt; As[4*tq+3][rm] = av.w * gt;
    }
#pragma unroll
    for (int p = 0; p < 2; ++p) {
      int rk = (t >> 5) + p*8, cn = (t & 31)*4;
      *(float4*)&Bs[rk][cn] = *(const float4*)(W2 + (size_t)(k0 + rk)*NOUT + cn);
    }
    __syncthreads();
#pragma unroll
    for (int kk = 0; kk < 16; ++kk) {
      float a[8], b[8];
      *(float4*)&a[0] = *(const float4*)&As[kk][4*ty];
      *(float4*)&a[4] = *(const float4*)&As[kk][64 + 4*ty];
      *(float4*)&b[0] = *(const float4*)&Bs[kk][4*tx];
      *(float4*)&b[4] = *(const float4*)&Bs[kk][64 + 4*tx];
#pragma unroll
      for (int i = 0; i < 8; ++i)
#pragma unroll
        for (int j = 0; j < 8; ++j)
          acc[i][j] = fmaf(a[i], b[j], acc[i][j]);
    }
    __syncthreads();
  }
#pragma unroll
  for (int ih = 0; ih < 2; ++ih)
#pragma unroll
    for (int i = 0; i < 4; ++i) {
      int r = row0 + ih*64 + 4*ty + i;
#pragma unroll
      for (int jh = 0; jh < 2; ++jh) {
        float4 v = make_float4(acc[ih*4+i][jh*4+0], acc[ih*4+i][jh*4+1],
                               acc[ih*4+i][jh*4+2], acc[ih*4+i][jh*4+3]);
        *(float4*)(xw2 + (size_t)r * NOUT + jh*64 + 4*tx) = v;
      }
    }
}

// ---- mega2r: build A2/As2 + agg+BN+PReLU (y2 in regs) + dots + scores + rank-out ----
__global__ __launch_bounds__(256) void mega2r(const int* __restrict__ ei,
                                              const float* __restrict__ ew,
                                              const int* __restrict__ nidx,
                                              const float* __restrict__ xw2,
                                              const float* __restrict__ gc2b,
                                              const float* __restrict__ g2,
                                              const float* __restrict__ be2,
                                              const float* __restrict__ mu2,
                                              const float* __restrict__ v2,
                                              const float* __restrict__ pa2,
                                              const float* __restrict__ pw2,
                                              const float* __restrict__ p2b,
                                              float* __restrict__ out) {
  int g = blockIdx.x, t = threadIdx.x;
  __shared__ float A2t[64*68];                 // [j][c] zero-padded
  __shared__ float As2s[K1_*K1_];
  __shared__ __align__(16) float xs[K1_*132];
  __shared__ float dg[K1_], dgs[K1_], dis[K1_], diss[K1_], d[K1_], s[K1_], gA[K1_];
  __shared__ int nm[C_], rankA[K1_];
  __shared__ float4 zpart[8][32];

  for (int i = t; i < 64*68; i += 256) A2t[i] = 0.f;
  for (int i = t; i < K1_*K1_; i += 256) As2s[i] = 0.f;
  if (t < C_) nm[t] = nidx[g*C_ + t];
  if (t < K1_) { dg[t] = 1.f; dgs[t] = 1.f; }
  for (int p = 0; p < 7; ++p) {
    int idx = t + p*256;
    if (idx < K1_*32) {
      int r = idx >> 5, f4 = idx & 31;
      *(float4*)&xs[r*132 + f4*4] =
          *(const float4*)(xw2 + ((size_t)g*K1_ + r)*NOUT + f4*4);
    }
  }
  int eR[2], eC[2]; float eW[2];
#pragma unroll
  for (int p = 0; p < 2; ++p) {
    int e = t + p*256;
    eR[p] = ei[e]; eC[p] = ei[E_ + e]; eW[p] = ew[e];
  }
  __syncthreads();
  int nr[2], nc[2]; bool val[2];
#pragma unroll
  for (int p = 0; p < 2; ++p) {
    nr[p] = nm[eR[p]]; nc[p] = nm[eC[p]];
    val[p] = (nr[p] >= 0) && (nc[p] >= 0);
    if (val[p]) { atomicAdd(&dg[nc[p]], eW[p]); atomicAdd(&dgs[nc[p]], 1.f); }
  }
  __syncthreads();
  if (t < K1_) { dis[t] = rsqrtf(dg[t]); diss[t] = rsqrtf(dgs[t]); }
  __syncthreads();
#pragma unroll
  for (int p = 0; p < 2; ++p) {
    if (val[p]) {
      atomicAdd(&A2t[nr[p]*68 + nc[p]],  dis[nr[p]] * eW[p] * dis[nc[p]]);
      atomicAdd(&As2s[nc[p]*K1_ + nr[p]], diss[nr[p]] * diss[nc[p]]);
    }
  }
  if (t < K1_) {
    atomicAdd(&A2t[t*68 + t],   dis[t]*dis[t]);
    atomicAdd(&As2s[t*K1_ + t], diss[t]*diss[t]);
  }
  __syncthreads();
  int tx = t & 31, ty = t >> 5;
  float4 scv, shv, pwv;
  {
    int col = 4*tx;
    float4 gv = *(const float4*)(g2 + col);
    float4 vv = *(const float4*)(v2 + col);
    float4 bv = *(const float4*)(be2 + col);
    float4 mv = *(const float4*)(mu2 + col);
    float4 b0 = *(const float4*)(gc2b + col);
    scv.x = gv.x * rsqrtf(vv.x + 1e-5f); scv.y = gv.y * rsqrtf(vv.y + 1e-5f);
    scv.z = gv.z * rsqrtf(vv.z + 1e-5f); scv.w = gv.w * rsqrtf(vv.w + 1e-5f);
    shv = make_float4((b0.x - mv.x)*scv.x + bv.x, (b0.y - mv.y)*scv.y + bv.y,
                      (b0.z - mv.z)*scv.z + bv.z, (b0.w - mv.w)*scv.w + bv.w);
    pwv = *(const float4*)(pw2 + col);
  }
  float a2v = pa2[0];
  float acc[8][4] = {};
  for (int j = 0; j < K1_; ++j) {
    float a[8];
    *(float4*)&a[0] = *(const float4*)&A2t[j*68 + ty*8];
    *(float4*)&a[4] = *(const float4*)&A2t[j*68 + ty*8 + 4];
    float4 xv = *(const float4*)&xs[j*132 + tx*4];
#pragma unroll
    for (int i = 0; i < 8; ++i) {
      acc[i][0] = fmaf(a[i], xv.x, acc[i][0]);
      acc[i][1] = fmaf(a[i], xv.y, acc[i][1]);
      acc[i][2] = fmaf(a[i], xv.z, acc[i][2]);
      acc[i][3] = fmaf(a[i], xv.w, acc[i][3]);
    }
  }
#pragma unroll
  for (int i = 0; i < 8; ++i) {
    int c = ty*8 + i;
    if (c < K1_) {
      float4 o;
      o.x = acc[i][0]*scv.x + shv.x; o.y = acc[i][1]*scv.y + shv.y;
      o.z = acc[i][2]*scv.z + shv.z; o.w = acc[i][3]*scv.w + shv.w;
      o.x = o.x >= 0.f ? o.x : a2v*o.x; o.y = o.y >= 0.f ? o.y : a2v*o.y;
      o.z = o.z >= 0.f ? o.z : a2v*o.z; o.w = o.w >= 0.f ? o.w : a2v*o.w;
      acc[i][0] = o.x; acc[i][1] = o.y; acc[i][2] = o.z; acc[i][3] = o.w;
      float dp = o.x*pwv.x + o.y*pwv.y + o.z*pwv.z + o.w*pwv.w;
      dp += __shfl_xor(dp, 1);
      dp += __shfl_xor(dp, 2);
      dp += __shfl_xor(dp, 4);
      dp += __shfl_xor(dp, 8);
      dp += __shfl_xor(dp, 16);
      if (tx == 0) d[c] = dp;
    }
  }
  __syncthreads();
  if (t < K1_) {
    float sv = p2b[0];
    for (int j = 0; j < K1_; ++j) sv = fmaf(As2s[t*K1_ + j], d[j], sv);
    s[t] = sv;
  }
  __syncthreads();
  if (t < K1_) {
    float si = s[t];
    int rank = 0;
    for (int j = 0; j < K1_; ++j) {
      float sj = s[j];
      rank += (sj > si) || (sj == si && j < t);
    }
    rankA[t] = rank;
    gA[t] = tanhf(si);
  }
  __syncthreads();
  float4 zp = make_float4(0.f, 0.f, 0.f, 0.f);
#pragma unroll
  for (int i = 0; i < 8; ++i) {
    int c = ty*8 + i;
    if (c < K1_) {
      int r = rankA[c];
      if (r < K2_) {
        float gt = gA[c];
        float4 v = make_float4(acc[i][0]*gt, acc[i][1]*gt, acc[i][2]*gt, acc[i][3]*gt);
        *(float4*)(out + ((size_t)g*K2_ + r)*NOUT + 4*tx) = v;
        zp.x += v.x; zp.y += v.y; zp.z += v.z; zp.w += v.w;
      }
    }
  }
  zpart[ty][tx] = zp;
  __syncthreads();
  if (t < 32) {
    float4 z = make_float4(0.f, 0.f, 0.f, 0.f);
#pragma unroll
    for (int k = 0; k < 8; ++k) {
      float4 v = zpart[k][t];
      z.x += v.x; z.y += v.y; z.z += v.z; z.w += v.w;
    }
    const float inv = 1.0f / (float)K2_;
    z.x *= inv; z.y *= inv; z.z *= inv; z.w *= inv;
    *(float4*)(out + (size_t)G_*K2_*NOUT + (size_t)g*NOUT + 4*t) = z;
  }
}

extern "C" void kernel_launch(void* const* d_in, const int* in_sizes, int n_in,
                              void* d_out, int out_size, void* d_ws, size_t ws_size,
                              hipStream_t stream) {
  const float* h    = (const float*)d_in[0];
  const int*   ei   = (const int*)  d_in[1];
  const float* ew   = (const float*)d_in[2];
  const float* gc1w = (const float*)d_in[3];
  const float* gc1b = (const float*)d_in[4];
  const float* bn1g = (const float*)d_in[5];
  const float* bn1b = (const float*)d_in[6];
  const float* bn1m = (const float*)d_in[7];
  const float* bn1v = (const float*)d_in[8];
  const float* pr1a = (const float*)d_in[9];
  const float* p1w  = (const float*)d_in[10];
  const float* p1b  = (const float*)d_in[11];
  const float* gc2w = (const float*)d_in[12];
  const float* gc2b = (const float*)d_in[13];
  const float* bn2g = (const float*)d_in[14];
  const float* bn2b = (const float*)d_in[15];
  const float* bn2m = (const float*)d_in[16];
  const float* bn2v = (const float*)d_in[17];
  const float* pr2a = (const float*)d_in[18];
  const float* p2w  = (const float*)d_in[19];
  const float* p2b  = (const float*)d_in[20];

  float* w = (float*)d_ws;
  // float offsets
  float*          A1      = w;                              // 4096
  float*          As1     = w + 4096;                       // 4096
  float*          dots2   = w + 8192;                       // 131072 (65536 x 2)
  int*            nidx    = (int*)(w + 139264);             // 65536
  int*            rowsrc  = (int*)(w + 204800);             // 53248
  float*          rowgate = w + 258048;                     // 53248
  unsigned short* W1thi   = (unsigned short*)(w + 311296);  // 32768 us = 16384 fl
  unsigned short* W1tlo   = (unsigned short*)(w + 327680);  // 16384 fl
  float*          xa2     = w + 344064;                     // 8388608
  float*          y1      = w + 8732672;                    // 16777216
  unsigned short* xahi    = (unsigned short*)(w + 25509888);// 8388608 us = 4194304 fl
  unsigned short* xalo    = (unsigned short*)(w + 29704192);// 4194304 fl -> end 33898496
  float*          xw2     = xa2;   // xa2 dead after xa_cvt

  build_A1<<<1, 256, 0, stream>>>(ei, ew, A1, As1);
  w1prep<<<64, 256, 0, stream>>>(gc1w, W1thi, W1tlo);
  preagg_b<<<1024, 256, 0, stream>>>(h, A1, xa2);
  xa_cvt<<<1024, 256, 0, stream>>>(xa2, xahi, xalo);
  gemm1m<<<dim3(1024, 2), 256, 0, stream>>>(xahi, xalo, W1thi, W1tlo, gc1b,
                                            bn1g, bn1b, bn1m, bn1v, pr1a, p1w,
                                            y1, dots2);
  pool1s<<<G_, 256, 0, stream>>>(dots2, As1, p1b, rowsrc, rowgate, nidx);
  gemm2g<<<416, 256, 0, stream>>>(y1, rowsrc, rowgate, gc2w, xw2);
  mega2r<<<G_, 256, 0, stream>>>(ei, ew, nidx, xw2, gc2b, bn2g, bn2b, bn2m, bn2v,
                                 pr2a, p2w, p2b, (float*)d_out);
}

// Round 10
// 155.145 us; speedup vs baseline: 2.1323x; 1.0670x over previous
//
#include <hip/hip_runtime.h>
#include <math.h>

#define B_   32
#define C_   64
#define F_   128
#define TP_  32
#define G_   (B_*TP_)      // 1024 graphs
#define NHID 256
#define NOUT 128
#define E_   512
#define K1_  52            // ceil(0.8*64)
#define K2_  42            // ceil(0.8*52)
#define N2_  (G_*K1_)      // 53248 rows layer 2

typedef __attribute__((ext_vector_type(8))) short short8_t;   // 8 bf16 (4 VGPR)
typedef __attribute__((ext_vector_type(4))) float f32x4_t;

__device__ __forceinline__ void split_bf16(float v, unsigned short &h, unsigned short &l) {
  unsigned u = __float_as_uint(v);
  unsigned hb = (u + 0x7FFFu + ((u >> 16) & 1u)) & 0xFFFF0000u;  // RNE bf16 of v
  float hf = __uint_as_float(hb);
  float r = v - hf;                                              // exact in f32
  unsigned ur = __float_as_uint(r);
  unsigned lb = (ur + 0x7FFFu + ((ur >> 16) & 1u)) >> 16;        // RNE bf16 of r
  h = (unsigned short)(hb >> 16);
  l = (unsigned short)lb;
}

__device__ __forceinline__ void split3_bf16(float v, unsigned short &h,
                                            unsigned short &m, unsigned short &l) {
  unsigned u = __float_as_uint(v);
  unsigned hb = (u + 0x7FFFu + ((u >> 16) & 1u)) & 0xFFFF0000u;
  float hf = __uint_as_float(hb);
  float r1 = v - hf;                                             // exact
  unsigned u1 = __float_as_uint(r1);
  unsigned mb = (u1 + 0x7FFFu + ((u1 >> 16) & 1u)) & 0xFFFF0000u;
  float mf = __uint_as_float(mb);
  float r2 = r1 - mf;                                            // exact
  unsigned u2 = __float_as_uint(r2);
  unsigned lb = (u2 + 0x7FFFu + ((u2 >> 16) & 1u)) >> 16;
  h = (unsigned short)(hb >> 16);
  m = (unsigned short)(mb >> 16);
  l = (unsigned short)lb;
}

// -------- build shared 64x64 A1 (edge-weight norm) and As1 (binary norm) -------------
__global__ __launch_bounds__(256) void build_A1(const int* __restrict__ ei,
                                                const float* __restrict__ ew,
                                                float* __restrict__ A1,
                                                float* __restrict__ As1) {
  __shared__ float A1s[C_*C_], As1s[C_*C_];
  __shared__ float dg[C_], dgs[C_], dis[C_], diss[C_];
  int t = threadIdx.x;
  for (int i = t; i < C_*C_; i += 256) { A1s[i] = 0.f; As1s[i] = 0.f; }
  if (t < C_) { dg[t] = 1.f; dgs[t] = 1.f; }   // self-loop weight 1
  int r0[2], c0[2]; float w0[2];
#pragma unroll
  for (int p = 0; p < 2; ++p) {
    int e = t + p*256;
    r0[p] = ei[e]; c0[p] = ei[E_ + e]; w0[p] = ew[e];
  }
  __syncthreads();
#pragma unroll
  for (int p = 0; p < 2; ++p) {
    atomicAdd(&dg[c0[p]], w0[p]);
    atomicAdd(&dgs[c0[p]], 1.f);
  }
  __syncthreads();
  if (t < C_) { dis[t] = rsqrtf(dg[t]); diss[t] = rsqrtf(dgs[t]); }
  __syncthreads();
#pragma unroll
  for (int p = 0; p < 2; ++p) {
    int r = r0[p], c = c0[p];
    atomicAdd(&A1s[c*C_ + r],  dis[r] * w0[p] * dis[c]);
    atomicAdd(&As1s[c*C_ + r], diss[r] * diss[c]);
  }
  if (t < C_) {
    atomicAdd(&A1s[t*C_ + t],  dis[t] * dis[t]);
    atomicAdd(&As1s[t*C_ + t], diss[t] * diss[t]);
  }
  __syncthreads();
  for (int i = t; i < C_*C_; i += 256) { A1[i] = A1s[i]; As1[i] = As1s[i]; }
}

// ---- w1prep: W1 [k 128][col 256] f32 -> W1t hi/lo [col][k] bf16 ----------------------
__global__ __launch_bounds__(256) void w1prep(const float* __restrict__ W1,
                                              unsigned short* __restrict__ Whi,
                                              unsigned short* __restrict__ Wlo) {
  int tid = blockIdx.x*256 + threadIdx.x;     // 16384 threads, 2 k's each
  int col = tid >> 6, k2 = tid & 63;
  float v0 = W1[(size_t)(2*k2)*NHID + col];
  float v1 = W1[(size_t)(2*k2+1)*NHID + col];
  unsigned short h0,l0,h1,l1;
  split_bf16(v0, h0, l0);
  split_bf16(v1, h1, l1);
  *(unsigned*)&Whi[(size_t)col*128 + 2*k2] = (unsigned)h0 | ((unsigned)h1 << 16);
  *(unsigned*)&Wlo[(size_t)col*128 + 2*k2] = (unsigned)l0 | ((unsigned)l1 << 16);
}

// ---- w2prep: W2 [k 256][col 128] f32 -> W2t hi/mid/lo [col][k 256] bf16 --------------
__global__ __launch_bounds__(256) void w2prep(const float* __restrict__ W2,
                                              unsigned short* __restrict__ Whi,
                                              unsigned short* __restrict__ Wmid,
                                              unsigned short* __restrict__ Wlo) {
  int tid = blockIdx.x*256 + threadIdx.x;     // 16384 threads, 2 k's each
  int col = tid >> 7, k2 = tid & 127;
  float v0 = W2[(size_t)(2*k2)*NOUT + col];
  float v1 = W2[(size_t)(2*k2+1)*NOUT + col];
  unsigned short h0,m0,l0,h1,m1,l1;
  split3_bf16(v0, h0, m0, l0);
  split3_bf16(v1, h1, m1, l1);
  *(unsigned*)&Whi [(size_t)col*256 + 2*k2] = (unsigned)h0 | ((unsigned)h1 << 16);
  *(unsigned*)&Wmid[(size_t)col*256 + 2*k2] = (unsigned)m0 | ((unsigned)m1 << 16);
  *(unsigned*)&Wlo [(size_t)col*256 + 2*k2] = (unsigned)l0 | ((unsigned)l1 << 16);
}

// ---- preagg: xa2[b,c,f,tp] = sum_j A1[c,j] * h[b,j,f,tp]  (per-b, (f,tp) cols) ------
__global__ __launch_bounds__(256) void preagg_b(const float* __restrict__ h,
                                                const float* __restrict__ A1,
                                                float* __restrict__ xa2) {
  int bid = blockIdx.x; int b = bid >> 5, q = bid & 31;   // q: 128-col chunk of 4096
  __shared__ float At[64*68];                              // A1 transposed [j][c]
  __shared__ __align__(16) float Hs[64*132];
  int t = threadIdx.x;
#pragma unroll
  for (int p = 0; p < 16; ++p) {
    int m = t + p*256;                      // A1[c*64+j]
    At[(m & 63)*68 + (m >> 6)] = A1[m];
  }
  const float* hb = h + ((size_t)b*64)*4096 + q*128;
#pragma unroll
  for (int p = 0; p < 8; ++p) {
    int idx = t + p*256;                    // 2048 float4 tiles: 64 j x 32 f4
    int j = idx >> 5, f4 = idx & 31;
    *(float4*)&Hs[j*132 + f4*4] = *(const float4*)(hb + (size_t)j*4096 + f4*4);
  }
  __syncthreads();
  int tx = t & 31, ty = t >> 5;             // tx: f4 col, ty: 8-row c block
  float acc[8][4] = {};
  for (int j = 0; j < 64; ++j) {
    float a[8];
    *(float4*)&a[0] = *(const float4*)&At[j*68 + ty*8];
    *(float4*)&a[4] = *(const float4*)&At[j*68 + ty*8 + 4];
    float4 hv = *(const float4*)&Hs[j*132 + tx*4];
#pragma unroll
    for (int i = 0; i < 8; ++i) {
      acc[i][0] = fmaf(a[i], hv.x, acc[i][0]);
      acc[i][1] = fmaf(a[i], hv.y, acc[i][1]);
      acc[i][2] = fmaf(a[i], hv.z, acc[i][2]);
      acc[i][3] = fmaf(a[i], hv.w, acc[i][3]);
    }
  }
  float* outp = xa2 + (((size_t)b*64) << 12) + q*128 + tx*4;
#pragma unroll
  for (int i = 0; i < 8; ++i) {
    int c = ty*8 + i;
    *(float4*)(outp + ((size_t)c << 12)) =
        make_float4(acc[i][0], acc[i][1], acc[i][2], acc[i][3]);
  }
}

// ---- xa_cvt: xa2 [b][c][f][tp] f32 -> xahi/xalo [R][k=f] bf16, R=(b*32+tp)*64+c -----
__global__ __launch_bounds__(256) void xa_cvt(const float* __restrict__ xa2,
                                              unsigned short* __restrict__ xahi,
                                              unsigned short* __restrict__ xalo) {
  int bid = blockIdx.x;                      // 1024: b = bid>>5, cpair
  int b = bid >> 5, c0 = (bid & 31) * 2;
  __shared__ float xs[8192];                 // [c_l 2][f 128][tp 32]
  int t = threadIdx.x;
  const float* src = xa2 + ((size_t)(b*64 + c0) << 12);
#pragma unroll
  for (int p = 0; p < 8; ++p) {
    int idx = (t + p*256) * 4;
    *(float4*)&xs[idx] = *(const float4*)(src + idx);
  }
  __syncthreads();
  int row_l = t >> 2, fq = t & 3;            // row_l = c_l*32+tp
  int c_l = row_l >> 5, tp = row_l & 31;
  size_t R = ((size_t)b*32 + tp)*64 + c0 + c_l;
  const float* base = &xs[c_l*4096 + tp];
#pragma unroll
  for (int i = 0; i < 4; ++i) {
    int f8 = fq + 4*i;
    unsigned hp[4], lp[4];
#pragma unroll
    for (int jj = 0; jj < 4; ++jj) {
      unsigned short h0,l0,h1,l1;
      split_bf16(base[(f8*8 + 2*jj    )*32], h0, l0);
      split_bf16(base[(f8*8 + 2*jj + 1)*32], h1, l1);
      hp[jj] = (unsigned)h0 | ((unsigned)h1 << 16);
      lp[jj] = (unsigned)l0 | ((unsigned)l1 << 16);
    }
    *(uint4*)&xahi[R*128 + f8*8] = make_uint4(hp[0], hp[1], hp[2], hp[3]);
    *(uint4*)&xalo[R*128 + f8*8] = make_uint4(lp[0], lp[1], lp[2], lp[3]);
  }
}

// ---- gemm1m: y1 = prelu(bn(xa @ W1 + b1)) via bf16x3 MFMA; y1 out as 3 bf16 limbs ---
// block: 64 rows x 128 cols (colhalf), 4 waves; wave = 64 rows x 32 cols (4x2 tiles)
__global__ __launch_bounds__(256) void gemm1m(const unsigned short* __restrict__ xahi,
                                              const unsigned short* __restrict__ xalo,
                                              const unsigned short* __restrict__ Whi,
                                              const unsigned short* __restrict__ Wlo,
                                              const float* __restrict__ gc1b,
                                              const float* __restrict__ g1,
                                              const float* __restrict__ be1,
                                              const float* __restrict__ mu1,
                                              const float* __restrict__ v1,
                                              const float* __restrict__ pa1,
                                              const float* __restrict__ pw1,
                                              unsigned short* __restrict__ y1hi,
                                              unsigned short* __restrict__ y1mid,
                                              unsigned short* __restrict__ y1lo,
                                              float* __restrict__ dots2) {
  __shared__ unsigned short Ahs[64*40], Als[64*40];     // [row][k32 pad40]
  __shared__ unsigned short Bhs[128*40], Bls[128*40];   // [col][k32 pad40]
  __shared__ float dsum[64*4];
  int t = threadIdx.x;
  int row0 = blockIdx.x * 64;
  int colhalf = blockIdx.y;
  int w = t >> 6, l = t & 63, lr = l & 15, lg = l >> 4;
  f32x4_t acc[4][2] = {};
  for (int k0 = 0; k0 < 128; k0 += 32) {
    {   // stage A: 64 rows x 32 k, 16B chunk per thread per plane
      int row = t >> 2, kq = t & 3;
      size_t src = (size_t)(row0 + row)*128 + k0 + kq*8;
      *(uint4*)&Ahs[row*40 + kq*8] = *(const uint4*)&xahi[src];
      *(uint4*)&Als[row*40 + kq*8] = *(const uint4*)&xalo[src];
    }
#pragma unroll
    for (int p = 0; p < 2; ++p) {   // stage B: 128 cols x 32 k
      int id = t + p*256;
      int colb = id >> 2, kq = id & 3;
      size_t src = (size_t)(colhalf*128 + colb)*128 + k0 + kq*8;
      *(uint4*)&Bhs[colb*40 + kq*8] = *(const uint4*)&Whi[src];
      *(uint4*)&Bls[colb*40 + kq*8] = *(const uint4*)&Wlo[src];
    }
    __syncthreads();
    short8_t ah[4], al[4], bh[2], bl[2];
#pragma unroll
    for (int s = 0; s < 4; ++s) {
      int off = (s*16 + lr)*40 + lg*8;
      ah[s] = *(const short8_t*)&Ahs[off];
      al[s] = *(const short8_t*)&Als[off];
    }
#pragma unroll
    for (int t2 = 0; t2 < 2; ++t2) {
      int off = (w*32 + t2*16 + lr)*40 + lg*8;
      bh[t2] = *(const short8_t*)&Bhs[off];
      bl[t2] = *(const short8_t*)&Bls[off];
    }
#pragma unroll
    for (int s = 0; s < 4; ++s)
#pragma unroll
      for (int t2 = 0; t2 < 2; ++t2) {
        acc[s][t2] = __builtin_amdgcn_mfma_f32_16x16x32_bf16(ah[s], bh[t2], acc[s][t2], 0, 0, 0);
        acc[s][t2] = __builtin_amdgcn_mfma_f32_16x16x32_bf16(al[s], bh[t2], acc[s][t2], 0, 0, 0);
        acc[s][t2] = __builtin_amdgcn_mfma_f32_16x16x32_bf16(ah[s], bl[t2], acc[s][t2], 0, 0, 0);
      }
    __syncthreads();
  }
  // epilogue: BN + PReLU + y1 (3 bf16 limbs) write + pool dot partials
  float sc_[2], sh_[2], pw_[2];
#pragma unroll
  for (int t2 = 0; t2 < 2; ++t2) {
    int col_g = colhalf*128 + w*32 + t2*16 + lr;
    float s = g1[col_g] * rsqrtf(v1[col_g] + 1e-5f);
    sc_[t2] = s;
    sh_[t2] = (gc1b[col_g] - mu1[col_g])*s + be1[col_g];
    pw_[t2] = pw1[col_g];
  }
  float a1v = pa1[0];
#pragma unroll
  for (int s = 0; s < 4; ++s)
#pragma unroll
    for (int j = 0; j < 4; ++j) {
      int row_l = s*16 + lg*4 + j;
      size_t R = (size_t)row0 + row_l;
      float d = 0.f;
#pragma unroll
      for (int t2 = 0; t2 < 2; ++t2) {
        float o = acc[s][t2][j]*sc_[t2] + sh_[t2];
        o = o >= 0.f ? o : a1v*o;
        unsigned short hh, mm, ll;
        split3_bf16(o, hh, mm, ll);
        size_t oi = R*NHID + colhalf*128 + w*32 + t2*16 + lr;
        y1hi[oi]  = hh;
        y1mid[oi] = mm;
        y1lo[oi]  = ll;
        d += o * pw_[t2];
      }
      d += __shfl_xor(d, 1);
      d += __shfl_xor(d, 2);
      d += __shfl_xor(d, 4);
      d += __shfl_xor(d, 8);
      if (lr == 0) dsum[row_l*4 + w] = d;
    }
  __syncthreads();
  if (t < 64)
    dots2[((size_t)row0 + t)*2 + colhalf] =
        (dsum[t*4+0] + dsum[t*4+1]) + (dsum[t*4+2] + dsum[t*4+3]);
}

// ---- pool1s: scores = As1 @ dots + b; stable top-52; emit rowsrc/rowgate/nidx -------
__global__ __launch_bounds__(256) void pool1s(const float* __restrict__ dots2,
                                              const float* __restrict__ As1,
                                              const float* __restrict__ p1b,
                                              int* __restrict__ rowsrc,
                                              float* __restrict__ rowgate,
                                              int* __restrict__ nidx) {
  int g = blockIdx.x, t = threadIdx.x;
  __shared__ float As1s[64*65];
  __shared__ float sp[64], s[64];
  __shared__ int perm[K1_];
  __shared__ float gate[K1_];
  for (int i = t; i < 4096; i += 256)
    As1s[(i >> 6)*65 + (i & 63)] = As1[i];
  if (t < 64) sp[t] = dots2[(g*64 + t)*2] + dots2[(g*64 + t)*2 + 1];
  __syncthreads();
  if (t < 64) {
    float acc = p1b[0];
    for (int j = 0; j < 64; ++j) acc = fmaf(As1s[t*65 + j], sp[j], acc);
    s[t] = acc;
  }
  __syncthreads();
  if (t < 64) {
    float si = s[t];
    int rank = 0;
    for (int j = 0; j < 64; ++j) {
      float sj = s[j];
      rank += (sj > si) || (sj == si && j < t);
    }
    nidx[g*64 + t] = (rank < K1_) ? rank : -1;
    if (rank < K1_) { perm[rank] = t; gate[rank] = tanhf(si); }
  }
  __syncthreads();
  if (t < K1_) {
    rowsrc[g*K1_ + t]  = g*64 + perm[t];
    rowgate[g*K1_ + t] = gate[t];
  }
}

// ---- gemm2m: xw2 = gathered(y1) @ W2 via 3-limb bf16 MFMA (f32-equivalent) ----------
// block: 64 gathered rows x 128 cols, 4 waves; K=256 in 8 steps of 32; 6 MFMA terms
__global__ __launch_bounds__(256) void gemm2m(const unsigned short* __restrict__ y1hi,
                                              const unsigned short* __restrict__ y1mid,
                                              const unsigned short* __restrict__ y1lo,
                                              const int* __restrict__ rowsrc,
                                              const unsigned short* __restrict__ Whi,
                                              const unsigned short* __restrict__ Wmid,
                                              const unsigned short* __restrict__ Wlo,
                                              float* __restrict__ xw2) {
  __shared__ unsigned short Ahs[64*40], Ams[64*40], Als[64*40];
  __shared__ unsigned short Bhs[128*40], Bms[128*40], Bls[128*40];
  int t = threadIdx.x;
  int row0 = blockIdx.x * 64;
  int w = t >> 6, l = t & 63, lr = l & 15, lg = l >> 4;
  int arow = t >> 2, akq = t & 3;
  size_t asrc = (size_t)rowsrc[row0 + arow] * NHID;
  f32x4_t acc[4][2] = {};
  for (int k0 = 0; k0 < NHID; k0 += 32) {
    {   // stage A (gathered rows), 3 planes
      size_t src = asrc + k0 + akq*8;
      *(uint4*)&Ahs[arow*40 + akq*8] = *(const uint4*)&y1hi[src];
      *(uint4*)&Ams[arow*40 + akq*8] = *(const uint4*)&y1mid[src];
      *(uint4*)&Als[arow*40 + akq*8] = *(const uint4*)&y1lo[src];
    }
#pragma unroll
    for (int p = 0; p < 2; ++p) {   // stage B: 128 cols x 32 k, 3 planes
      int id = t + p*256;
      int colb = id >> 2, kq = id & 3;
      size_t src = (size_t)colb*256 + k0 + kq*8;
      *(uint4*)&Bhs[colb*40 + kq*8] = *(const uint4*)&Whi[src];
      *(uint4*)&Bms[colb*40 + kq*8] = *(const uint4*)&Wmid[src];
      *(uint4*)&Bls[colb*40 + kq*8] = *(const uint4*)&Wlo[src];
    }
    __syncthreads();
    short8_t ah[4], am[4], al[4], bh[2], bm[2], bl[2];
#pragma unroll
    for (int s = 0; s < 4; ++s) {
      int off = (s*16 + lr)*40 + lg*8;
      ah[s] = *(const short8_t*)&Ahs[off];
      am[s] = *(const short8_t*)&Ams[off];
      al[s] = *(const short8_t*)&Als[off];
    }
#pragma unroll
    for (int t2 = 0; t2 < 2; ++t2) {
      int off = (w*32 + t2*16 + lr)*40 + lg*8;
      bh[t2] = *(const short8_t*)&Bhs[off];
      bm[t2] = *(const short8_t*)&Bms[off];
      bl[t2] = *(const short8_t*)&Bls[off];
    }
#pragma unroll
    for (int s = 0; s < 4; ++s)
#pragma unroll
      for (int t2 = 0; t2 < 2; ++t2) {
        acc[s][t2] = __builtin_amdgcn_mfma_f32_16x16x32_bf16(ah[s], bh[t2], acc[s][t2], 0, 0, 0);
        acc[s][t2] = __builtin_amdgcn_mfma_f32_16x16x32_bf16(ah[s], bm[t2], acc[s][t2], 0, 0, 0);
        acc[s][t2] = __builtin_amdgcn_mfma_f32_16x16x32_bf16(am[s], bh[t2], acc[s][t2], 0, 0, 0);
        acc[s][t2] = __builtin_amdgcn_mfma_f32_16x16x32_bf16(ah[s], bl[t2], acc[s][t2], 0, 0, 0);
        acc[s][t2] = __builtin_amdgcn_mfma_f32_16x16x32_bf16(am[s], bm[t2], acc[s][t2], 0, 0, 0);
        acc[s][t2] = __builtin_amdgcn_mfma_f32_16x16x32_bf16(al[s], bh[t2], acc[s][t2], 0, 0, 0);
      }
    __syncthreads();
  }
#pragma unroll
  for (int s = 0; s < 4; ++s)
#pragma unroll
    for (int t2 = 0; t2 < 2; ++t2)
#pragma unroll
      for (int j = 0; j < 4; ++j) {
        int row_l = s*16 + lg*4 + j;
        int col = w*32 + t2*16 + lr;
        xw2[(size_t)(row0 + row_l)*NOUT + col] = acc[s][t2][j];
      }
}

// ---- mega2r: build A2/As2 + gate-on-load + agg+BN+PReLU + dots + scores + rank-out --
__global__ __launch_bounds__(256) void mega2r(const int* __restrict__ ei,
                                              const float* __restrict__ ew,
                                              const int* __restrict__ nidx,
                                              const float* __restrict__ xw2,
                                              const float* __restrict__ rowgate,
                                              const float* __restrict__ gc2b,
                                              const float* __restrict__ g2,
                                              const float* __restrict__ be2,
                                              const float* __restrict__ mu2,
                                              const float* __restrict__ v2,
                                              const float* __restrict__ pa2,
                                              const float* __restrict__ pw2,
                                              const float* __restrict__ p2b,
                                              float* __restrict__ out) {
  int g = blockIdx.x, t = threadIdx.x;
  __shared__ float A2t[64*68];                 // [j][c] zero-padded
  __shared__ float As2s[K1_*K1_];
  __shared__ __align__(16) float xs[K1_*132];
  __shared__ float dg[K1_], dgs[K1_], dis[K1_], diss[K1_], d[K1_], s[K1_], gA[K1_];
  __shared__ int nm[C_], rankA[K1_];
  __shared__ float4 zpart[8][32];

  for (int i = t; i < 64*68; i += 256) A2t[i] = 0.f;
  for (int i = t; i < K1_*K1_; i += 256) As2s[i] = 0.f;
  if (t < C_) nm[t] = nidx[g*C_ + t];
  if (t < K1_) { dg[t] = 1.f; dgs[t] = 1.f; }
  for (int p = 0; p < 7; ++p) {
    int idx = t + p*256;
    if (idx < K1_*32) {
      int r = idx >> 5, f4 = idx & 31;
      float gt = rowgate[g*K1_ + r];
      float4 v = *(const float4*)(xw2 + ((size_t)g*K1_ + r)*NOUT + f4*4);
      v.x *= gt; v.y *= gt; v.z *= gt; v.w *= gt;
      *(float4*)&xs[r*132 + f4*4] = v;
    }
  }
  int eR[2], eC[2]; float eW[2];
#pragma unroll
  for (int p = 0; p < 2; ++p) {
    int e = t + p*256;
    eR[p] = ei[e]; eC[p] = ei[E_ + e]; eW[p] = ew[e];
  }
  __syncthreads();
  int nr[2], nc[2]; bool val[2];
#pragma unroll
  for (int p = 0; p < 2; ++p) {
    nr[p] = nm[eR[p]]; nc[p] = nm[eC[p]];
    val[p] = (nr[p] >= 0) && (nc[p] >= 0);
    if (val[p]) { atomicAdd(&dg[nc[p]], eW[p]); atomicAdd(&dgs[nc[p]], 1.f); }
  }
  __syncthreads();
  if (t < K1_) { dis[t] = rsqrtf(dg[t]); diss[t] = rsqrtf(dgs[t]); }
  __syncthreads();
#pragma unroll
  for (int p = 0; p < 2; ++p) {
    if (val[p]) {
      atomicAdd(&A2t[nr[p]*68 + nc[p]],  dis[nr[p]] * eW[p] * dis[nc[p]]);
      atomicAdd(&As2s[nc[p]*K1_ + nr[p]], diss[nr[p]] * diss[nc[p]]);
    }
  }
  if (t < K1_) {
    atomicAdd(&A2t[t*68 + t],   dis[t]*dis[t]);
    atomicAdd(&As2s[t*K1_ + t], diss[t]*diss[t]);
  }
  __syncthreads();
  int tx = t & 31, ty = t >> 5;
  float4 scv, shv, pwv;
  {
    int col = 4*tx;
    float4 gv = *(const float4*)(g2 + col);
    float4 vv = *(const float4*)(v2 + col);
    float4 bv = *(const float4*)(be2 + col);
    float4 mv = *(const float4*)(mu2 + col);
    float4 b0 = *(const float4*)(gc2b + col);
    scv.x = gv.x * rsqrtf(vv.x + 1e-5f); scv.y = gv.y * rsqrtf(vv.y + 1e-5f);
    scv.z = gv.z * rsqrtf(vv.z + 1e-5f); scv.w = gv.w * rsqrtf(vv.w + 1e-5f);
    shv = make_float4((b0.x - mv.x)*scv.x + bv.x, (b0.y - mv.y)*scv.y + bv.y,
                      (b0.z - mv.z)*scv.z + bv.z, (b0.w - mv.w)*scv.w + bv.w);
    pwv = *(const float4*)(pw2 + col);
  }
  float a2v = pa2[0];
  float acc[8][4] = {};
  for (int j = 0; j < K1_; ++j) {
    float a[8];
    *(float4*)&a[0] = *(const float4*)&A2t[j*68 + ty*8];
    *(float4*)&a[4] = *(const float4*)&A2t[j*68 + ty*8 + 4];
    float4 xv = *(const float4*)&xs[j*132 + tx*4];
#pragma unroll
    for (int i = 0; i < 8; ++i) {
      acc[i][0] = fmaf(a[i], xv.x, acc[i][0]);
      acc[i][1] = fmaf(a[i], xv.y, acc[i][1]);
      acc[i][2] = fmaf(a[i], xv.z, acc[i][2]);
      acc[i][3] = fmaf(a[i], xv.w, acc[i][3]);
    }
  }
#pragma unroll
  for (int i = 0; i < 8; ++i) {
    int c = ty*8 + i;
    if (c < K1_) {
      float4 o;
      o.x = acc[i][0]*scv.x + shv.x; o.y = acc[i][1]*scv.y + shv.y;
      o.z = acc[i][2]*scv.z + shv.z; o.w = acc[i][3]*scv.w + shv.w;
      o.x = o.x >= 0.f ? o.x : a2v*o.x; o.y = o.y >= 0.f ? o.y : a2v*o.y;
      o.z = o.z >= 0.f ? o.z : a2v*o.z; o.w = o.w >= 0.f ? o.w : a2v*o.w;
      acc[i][0] = o.x; acc[i][1] = o.y; acc[i][2] = o.z; acc[i][3] = o.w;
      float dp = o.x*pwv.x + o.y*pwv.y + o.z*pwv.z + o.w*pwv.w;
      dp += __shfl_xor(dp, 1);
      dp += __shfl_xor(dp, 2);
      dp += __shfl_xor(dp, 4);
      dp += __shfl_xor(dp, 8);
      dp += __shfl_xor(dp, 16);
      if (tx == 0) d[c] = dp;
    }
  }
  __syncthreads();
  if (t < K1_) {
    float sv = p2b[0];
    for (int j = 0; j < K1_; ++j) sv = fmaf(As2s[t*K1_ + j], d[j], sv);
    s[t] = sv;
  }
  __syncthreads();
  if (t < K1_) {
    float si = s[t];
    int rank = 0;
    for (int j = 0; j < K1_; ++j) {
      float sj = s[j];
      rank += (sj > si) || (sj == si && j < t);
    }
    rankA[t] = rank;
    gA[t] = tanhf(si);
  }
  __syncthreads();
  float4 zp = make_float4(0.f, 0.f, 0.f, 0.f);
#pragma unroll
  for (int i = 0; i < 8; ++i) {
    int c = ty*8 + i;
    if (c < K1_) {
      int r = rankA[c];
      if (r < K2_) {
        float gt = gA[c];
        float4 v = make_float4(acc[i][0]*gt, acc[i][1]*gt, acc[i][2]*gt, acc[i][3]*gt);
        *(float4*)(out + ((size_t)g*K2_ + r)*NOUT + 4*tx) = v;
        zp.x += v.x; zp.y += v.y; zp.z += v.z; zp.w += v.w;
      }
    }
  }
  zpart[ty][tx] = zp;
  __syncthreads();
  if (t < 32) {
    float4 z = make_float4(0.f, 0.f, 0.f, 0.f);
#pragma unroll
    for (int k = 0; k < 8; ++k) {
      float4 v = zpart[k][t];
      z.x += v.x; z.y += v.y; z.z += v.z; z.w += v.w;
    }
    const float inv = 1.0f / (float)K2_;
    z.x *= inv; z.y *= inv; z.z *= inv; z.w *= inv;
    *(float4*)(out + (size_t)G_*K2_*NOUT + (size_t)g*NOUT + 4*t) = z;
  }
}

extern "C" void kernel_launch(void* const* d_in, const int* in_sizes, int n_in,
                              void* d_out, int out_size, void* d_ws, size_t ws_size,
                              hipStream_t stream) {
  const float* h    = (const float*)d_in[0];
  const int*   ei   = (const int*)  d_in[1];
  const float* ew   = (const float*)d_in[2];
  const float* gc1w = (const float*)d_in[3];
  const float* gc1b = (const float*)d_in[4];
  const float* bn1g = (const float*)d_in[5];
  const float* bn1b = (const float*)d_in[6];
  const float* bn1m = (const float*)d_in[7];
  const float* bn1v = (const float*)d_in[8];
  const float* pr1a = (const float*)d_in[9];
  const float* p1w  = (const float*)d_in[10];
  const float* p1b  = (const float*)d_in[11];
  const float* gc2w = (const float*)d_in[12];
  const float* gc2b = (const float*)d_in[13];
  const float* bn2g = (const float*)d_in[14];
  const float* bn2b = (const float*)d_in[15];
  const float* bn2m = (const float*)d_in[16];
  const float* bn2v = (const float*)d_in[17];
  const float* pr2a = (const float*)d_in[18];
  const float* p2w  = (const float*)d_in[19];
  const float* p2b  = (const float*)d_in[20];

  float* w = (float*)d_ws;
  // float offsets
  float*          A1      = w;                               // 4096
  float*          As1     = w + 4096;                        // 4096
  float*          dots2   = w + 8192;                        // 131072
  int*            nidx    = (int*)(w + 139264);              // 65536
  int*            rowsrc  = (int*)(w + 204800);              // 53248
  float*          rowgate = w + 258048;                      // 53248
  unsigned short* W1thi   = (unsigned short*)(w + 311296);   // 16384 fl
  unsigned short* W1tlo   = (unsigned short*)(w + 327680);   // 16384 fl
  unsigned short* W2thi   = (unsigned short*)(w + 344064);   // 16384 fl
  unsigned short* W2tmid  = (unsigned short*)(w + 360448);   // 16384 fl
  unsigned short* W2tlo   = (unsigned short*)(w + 376832);   // 16384 fl
  float*          xa2     = w + 393216;                      // 8388608
  unsigned short* xahi    = (unsigned short*)(w + 8781824);  // 4194304 fl
  unsigned short* xalo    = (unsigned short*)(w + 12976128); // 4194304 fl
  unsigned short* y1hi    = (unsigned short*)(w + 17170432); // 8388608 fl
  unsigned short* y1mid   = (unsigned short*)(w + 25559040); // 8388608 fl
  unsigned short* y1lo    = (unsigned short*)(w + 33947648); // 8388608 fl -> 42336256
  float*          xw2     = xa2;   // xa2 dead after xa_cvt

  build_A1<<<1, 256, 0, stream>>>(ei, ew, A1, As1);
  w1prep<<<64, 256, 0, stream>>>(gc1w, W1thi, W1tlo);
  w2prep<<<64, 256, 0, stream>>>(gc2w, W2thi, W2tmid, W2tlo);
  preagg_b<<<1024, 256, 0, stream>>>(h, A1, xa2);
  xa_cvt<<<1024, 256, 0, stream>>>(xa2, xahi, xalo);
  gemm1m<<<dim3(1024, 2), 256, 0, stream>>>(xahi, xalo, W1thi, W1tlo, gc1b,
                                            bn1g, bn1b, bn1m, bn1v, pr1a, p1w,
                                            y1hi, y1mid, y1lo, dots2);
  pool1s<<<G_, 256, 0, stream>>>(dots2, As1, p1b, rowsrc, rowgate, nidx);
  gemm2m<<<832, 256, 0, stream>>>(y1hi, y1mid, y1lo, rowsrc, W2thi, W2tmid, W2tlo, xw2);
  mega2r<<<G_, 256, 0, stream>>>(ei, ew, nidx, xw2, rowgate, gc2b, bn2g, bn2b,
                                 bn2m, bn2v, pr2a, p2w, p2b, (float*)d_out);
}

// Round 11
// 147.686 us; speedup vs baseline: 2.2400x; 1.0505x over previous
//
#include <hip/hip_runtime.h>
#include <math.h>

#define B_   32
#define C_   64
#define F_   128
#define TP_  32
#define G_   (B_*TP_)      // 1024 graphs
#define NHID 256
#define NOUT 128
#define E_   512
#define K1_  52            // ceil(0.8*64)
#define K2_  42            // ceil(0.8*52)
#define N2_  (G_*K1_)      // 53248 rows layer 2

typedef __attribute__((ext_vector_type(8))) short short8_t;   // 8 bf16 (4 VGPR)
typedef __attribute__((ext_vector_type(4))) float f32x4_t;

__device__ __forceinline__ void split_bf16(float v, unsigned short &h, unsigned short &l) {
  unsigned u = __float_as_uint(v);
  unsigned hb = (u + 0x7FFFu + ((u >> 16) & 1u)) & 0xFFFF0000u;  // RNE bf16 of v
  float hf = __uint_as_float(hb);
  float r = v - hf;                                              // exact in f32
  unsigned ur = __float_as_uint(r);
  unsigned lb = (ur + 0x7FFFu + ((ur >> 16) & 1u)) >> 16;        // RNE bf16 of r
  h = (unsigned short)(hb >> 16);
  l = (unsigned short)lb;
}

__device__ __forceinline__ void split3_bf16(float v, unsigned short &h,
                                            unsigned short &m, unsigned short &l) {
  unsigned u = __float_as_uint(v);
  unsigned hb = (u + 0x7FFFu + ((u >> 16) & 1u)) & 0xFFFF0000u;
  float hf = __uint_as_float(hb);
  float r1 = v - hf;                                             // exact
  unsigned u1 = __float_as_uint(r1);
  unsigned mb = (u1 + 0x7FFFu + ((u1 >> 16) & 1u)) & 0xFFFF0000u;
  float mf = __uint_as_float(mb);
  float r2 = r1 - mf;                                            // exact
  unsigned u2 = __float_as_uint(r2);
  unsigned lb = (u2 + 0x7FFFu + ((u2 >> 16) & 1u)) >> 16;
  h = (unsigned short)(hb >> 16);
  m = (unsigned short)(mb >> 16);
  l = (unsigned short)lb;
}

// -------- build shared 64x64 A1 (edge-weight norm) and As1 (binary norm) -------------
__global__ __launch_bounds__(256) void build_A1(const int* __restrict__ ei,
                                                const float* __restrict__ ew,
                                                float* __restrict__ A1,
                                                float* __restrict__ As1) {
  __shared__ float A1s[C_*C_], As1s[C_*C_];
  __shared__ float dg[C_], dgs[C_], dis[C_], diss[C_];
  int t = threadIdx.x;
  for (int i = t; i < C_*C_; i += 256) { A1s[i] = 0.f; As1s[i] = 0.f; }
  if (t < C_) { dg[t] = 1.f; dgs[t] = 1.f; }   // self-loop weight 1
  int r0[2], c0[2]; float w0[2];
#pragma unroll
  for (int p = 0; p < 2; ++p) {
    int e = t + p*256;
    r0[p] = ei[e]; c0[p] = ei[E_ + e]; w0[p] = ew[e];
  }
  __syncthreads();
#pragma unroll
  for (int p = 0; p < 2; ++p) {
    atomicAdd(&dg[c0[p]], w0[p]);
    atomicAdd(&dgs[c0[p]], 1.f);
  }
  __syncthreads();
  if (t < C_) { dis[t] = rsqrtf(dg[t]); diss[t] = rsqrtf(dgs[t]); }
  __syncthreads();
#pragma unroll
  for (int p = 0; p < 2; ++p) {
    int r = r0[p], c = c0[p];
    atomicAdd(&A1s[c*C_ + r],  dis[r] * w0[p] * dis[c]);
    atomicAdd(&As1s[c*C_ + r], diss[r] * diss[c]);
  }
  if (t < C_) {
    atomicAdd(&A1s[t*C_ + t],  dis[t] * dis[t]);
    atomicAdd(&As1s[t*C_ + t], diss[t] * diss[t]);
  }
  __syncthreads();
  for (int i = t; i < C_*C_; i += 256) { A1[i] = A1s[i]; As1[i] = As1s[i]; }
}

// ---- w1prep: W1 [k 128][col 256] f32 -> W1t hi/lo [col][k] bf16 ----------------------
__global__ __launch_bounds__(256) void w1prep(const float* __restrict__ W1,
                                              unsigned short* __restrict__ Whi,
                                              unsigned short* __restrict__ Wlo) {
  int tid = blockIdx.x*256 + threadIdx.x;     // 16384 threads, 2 k's each
  int col = tid >> 6, k2 = tid & 63;
  float v0 = W1[(size_t)(2*k2)*NHID + col];
  float v1 = W1[(size_t)(2*k2+1)*NHID + col];
  unsigned short h0,l0,h1,l1;
  split_bf16(v0, h0, l0);
  split_bf16(v1, h1, l1);
  *(unsigned*)&Whi[(size_t)col*128 + 2*k2] = (unsigned)h0 | ((unsigned)h1 << 16);
  *(unsigned*)&Wlo[(size_t)col*128 + 2*k2] = (unsigned)l0 | ((unsigned)l1 << 16);
}

// ---- w2prep: W2 [k 256][col 128] f32 -> W2t hi/mid/lo [col][k 256] bf16 --------------
__global__ __launch_bounds__(256) void w2prep(const float* __restrict__ W2,
                                              unsigned short* __restrict__ Whi,
                                              unsigned short* __restrict__ Wmid,
                                              unsigned short* __restrict__ Wlo) {
  int tid = blockIdx.x*256 + threadIdx.x;     // 16384 threads, 2 k's each
  int col = tid >> 7, k2 = tid & 127;
  float v0 = W2[(size_t)(2*k2)*NOUT + col];
  float v1 = W2[(size_t)(2*k2+1)*NOUT + col];
  unsigned short h0,m0,l0,h1,m1,l1;
  split3_bf16(v0, h0, m0, l0);
  split3_bf16(v1, h1, m1, l1);
  *(unsigned*)&Whi [(size_t)col*256 + 2*k2] = (unsigned)h0 | ((unsigned)h1 << 16);
  *(unsigned*)&Wmid[(size_t)col*256 + 2*k2] = (unsigned)m0 | ((unsigned)m1 << 16);
  *(unsigned*)&Wlo [(size_t)col*256 + 2*k2] = (unsigned)l0 | ((unsigned)l1 << 16);
}

// ---- preagg: xa2[b,c,f,tp] = sum_j A1[c,j] * h[b,j,f,tp]  (per-b, (f,tp) cols) ------
__global__ __launch_bounds__(256) void preagg_b(const float* __restrict__ h,
                                                const float* __restrict__ A1,
                                                float* __restrict__ xa2) {
  int bid = blockIdx.x; int b = bid >> 5, q = bid & 31;   // q: 128-col chunk of 4096
  __shared__ float At[64*68];                              // A1 transposed [j][c]
  __shared__ __align__(16) float Hs[64*132];
  int t = threadIdx.x;
#pragma unroll
  for (int p = 0; p < 16; ++p) {
    int m = t + p*256;                      // A1[c*64+j]
    At[(m & 63)*68 + (m >> 6)] = A1[m];
  }
  const float* hb = h + ((size_t)b*64)*4096 + q*128;
#pragma unroll
  for (int p = 0; p < 8; ++p) {
    int idx = t + p*256;                    // 2048 float4 tiles: 64 j x 32 f4
    int j = idx >> 5, f4 = idx & 31;
    *(float4*)&Hs[j*132 + f4*4] = *(const float4*)(hb + (size_t)j*4096 + f4*4);
  }
  __syncthreads();
  int tx = t & 31, ty = t >> 5;             // tx: f4 col, ty: 8-row c block
  float acc[8][4] = {};
  for (int j = 0; j < 64; ++j) {
    float a[8];
    *(float4*)&a[0] = *(const float4*)&At[j*68 + ty*8];
    *(float4*)&a[4] = *(const float4*)&At[j*68 + ty*8 + 4];
    float4 hv = *(const float4*)&Hs[j*132 + tx*4];
#pragma unroll
    for (int i = 0; i < 8; ++i) {
      acc[i][0] = fmaf(a[i], hv.x, acc[i][0]);
      acc[i][1] = fmaf(a[i], hv.y, acc[i][1]);
      acc[i][2] = fmaf(a[i], hv.z, acc[i][2]);
      acc[i][3] = fmaf(a[i], hv.w, acc[i][3]);
    }
  }
  float* outp = xa2 + (((size_t)b*64) << 12) + q*128 + tx*4;
#pragma unroll
  for (int i = 0; i < 8; ++i) {
    int c = ty*8 + i;
    *(float4*)(outp + ((size_t)c << 12)) =
        make_float4(acc[i][0], acc[i][1], acc[i][2], acc[i][3]);
  }
}

// ---- xa_cvt: xa2 [b][c][f][tp] f32 -> xahi/xalo [R][k=f] bf16, R=(b*32+tp)*64+c -----
__global__ __launch_bounds__(256) void xa_cvt(const float* __restrict__ xa2,
                                              unsigned short* __restrict__ xahi,
                                              unsigned short* __restrict__ xalo) {
  int bid = blockIdx.x;                      // 1024: b = bid>>5, cpair
  int b = bid >> 5, c0 = (bid & 31) * 2;
  __shared__ float xs[8192];                 // [c_l 2][f 128][tp 32]
  int t = threadIdx.x;
  const float* src = xa2 + ((size_t)(b*64 + c0) << 12);
#pragma unroll
  for (int p = 0; p < 8; ++p) {
    int idx = (t + p*256) * 4;
    *(float4*)&xs[idx] = *(const float4*)(src + idx);
  }
  __syncthreads();
  int row_l = t >> 2, fq = t & 3;            // row_l = c_l*32+tp
  int c_l = row_l >> 5, tp = row_l & 31;
  size_t R = ((size_t)b*32 + tp)*64 + c0 + c_l;
  const float* base = &xs[c_l*4096 + tp];
#pragma unroll
  for (int i = 0; i < 4; ++i) {
    int f8 = fq + 4*i;
    unsigned hp[4], lp[4];
#pragma unroll
    for (int jj = 0; jj < 4; ++jj) {
      unsigned short h0,l0,h1,l1;
      split_bf16(base[(f8*8 + 2*jj    )*32], h0, l0);
      split_bf16(base[(f8*8 + 2*jj + 1)*32], h1, l1);
      hp[jj] = (unsigned)h0 | ((unsigned)h1 << 16);
      lp[jj] = (unsigned)l0 | ((unsigned)l1 << 16);
    }
    *(uint4*)&xahi[R*128 + f8*8] = make_uint4(hp[0], hp[1], hp[2], hp[3]);
    *(uint4*)&xalo[R*128 + f8*8] = make_uint4(lp[0], lp[1], lp[2], lp[3]);
  }
}

// ---- gemm1m: y1 = prelu(bn(xa @ W1 + b1)) via bf16x3 MFMA; y1 out as f32 ------------
// block: 64 rows x 128 cols (colhalf), 4 waves; wave = 64 rows x 32 cols (4x2 tiles)
__global__ __launch_bounds__(256) void gemm1m(const unsigned short* __restrict__ xahi,
                                              const unsigned short* __restrict__ xalo,
                                              const unsigned short* __restrict__ Whi,
                                              const unsigned short* __restrict__ Wlo,
                                              const float* __restrict__ gc1b,
                                              const float* __restrict__ g1,
                                              const float* __restrict__ be1,
                                              const float* __restrict__ mu1,
                                              const float* __restrict__ v1,
                                              const float* __restrict__ pa1,
                                              const float* __restrict__ pw1,
                                              float* __restrict__ y1,
                                              float* __restrict__ dots2) {
  __shared__ unsigned short Ahs[64*40], Als[64*40];     // [row][k32 pad40]
  __shared__ unsigned short Bhs[128*40], Bls[128*40];   // [col][k32 pad40]
  __shared__ float dsum[64*4];
  int t = threadIdx.x;
  int row0 = blockIdx.x * 64;
  int colhalf = blockIdx.y;
  int w = t >> 6, l = t & 63, lr = l & 15, lg = l >> 4;
  f32x4_t acc[4][2] = {};
  for (int k0 = 0; k0 < 128; k0 += 32) {
    {   // stage A: 64 rows x 32 k, 16B chunk per thread per plane
      int row = t >> 2, kq = t & 3;
      size_t src = (size_t)(row0 + row)*128 + k0 + kq*8;
      *(uint4*)&Ahs[row*40 + kq*8] = *(const uint4*)&xahi[src];
      *(uint4*)&Als[row*40 + kq*8] = *(const uint4*)&xalo[src];
    }
#pragma unroll
    for (int p = 0; p < 2; ++p) {   // stage B: 128 cols x 32 k
      int id = t + p*256;
      int colb = id >> 2, kq = id & 3;
      size_t src = (size_t)(colhalf*128 + colb)*128 + k0 + kq*8;
      *(uint4*)&Bhs[colb*40 + kq*8] = *(const uint4*)&Whi[src];
      *(uint4*)&Bls[colb*40 + kq*8] = *(const uint4*)&Wlo[src];
    }
    __syncthreads();
    short8_t ah[4], al[4], bh[2], bl[2];
#pragma unroll
    for (int s = 0; s < 4; ++s) {
      int off = (s*16 + lr)*40 + lg*8;
      ah[s] = *(const short8_t*)&Ahs[off];
      al[s] = *(const short8_t*)&Als[off];
    }
#pragma unroll
    for (int t2 = 0; t2 < 2; ++t2) {
      int off = (w*32 + t2*16 + lr)*40 + lg*8;
      bh[t2] = *(const short8_t*)&Bhs[off];
      bl[t2] = *(const short8_t*)&Bls[off];
    }
#pragma unroll
    for (int s = 0; s < 4; ++s)
#pragma unroll
      for (int t2 = 0; t2 < 2; ++t2) {
        acc[s][t2] = __builtin_amdgcn_mfma_f32_16x16x32_bf16(ah[s], bh[t2], acc[s][t2], 0, 0, 0);
        acc[s][t2] = __builtin_amdgcn_mfma_f32_16x16x32_bf16(al[s], bh[t2], acc[s][t2], 0, 0, 0);
        acc[s][t2] = __builtin_amdgcn_mfma_f32_16x16x32_bf16(ah[s], bl[t2], acc[s][t2], 0, 0, 0);
      }
    __syncthreads();
  }
  // epilogue: BN + PReLU + y1 (f32) write + pool dot partials
  float sc_[2], sh_[2], pw_[2];
#pragma unroll
  for (int t2 = 0; t2 < 2; ++t2) {
    int col_g = colhalf*128 + w*32 + t2*16 + lr;
    float s = g1[col_g] * rsqrtf(v1[col_g] + 1e-5f);
    sc_[t2] = s;
    sh_[t2] = (gc1b[col_g] - mu1[col_g])*s + be1[col_g];
    pw_[t2] = pw1[col_g];
  }
  float a1v = pa1[0];
#pragma unroll
  for (int s = 0; s < 4; ++s)
#pragma unroll
    for (int j = 0; j < 4; ++j) {
      int row_l = s*16 + lg*4 + j;
      size_t R = (size_t)row0 + row_l;
      float d = 0.f;
#pragma unroll
      for (int t2 = 0; t2 < 2; ++t2) {
        float o = acc[s][t2][j]*sc_[t2] + sh_[t2];
        o = o >= 0.f ? o : a1v*o;
        y1[R*NHID + colhalf*128 + w*32 + t2*16 + lr] = o;
        d += o * pw_[t2];
      }
      d += __shfl_xor(d, 1);
      d += __shfl_xor(d, 2);
      d += __shfl_xor(d, 4);
      d += __shfl_xor(d, 8);
      if (lr == 0) dsum[row_l*4 + w] = d;
    }
  __syncthreads();
  if (t < 64)
    dots2[((size_t)row0 + t)*2 + colhalf] =
        (dsum[t*4+0] + dsum[t*4+1]) + (dsum[t*4+2] + dsum[t*4+3]);
}

// ---- pool1s: scores = As1 @ dots + b; stable top-52; emit rowsrc/rowgate/nidx -------
__global__ __launch_bounds__(256) void pool1s(const float* __restrict__ dots2,
                                              const float* __restrict__ As1,
                                              const float* __restrict__ p1b,
                                              int* __restrict__ rowsrc,
                                              float* __restrict__ rowgate,
                                              int* __restrict__ nidx) {
  int g = blockIdx.x, t = threadIdx.x;
  __shared__ float As1s[64*65];
  __shared__ float sp[64], s[64];
  __shared__ int perm[K1_];
  __shared__ float gate[K1_];
  for (int i = t; i < 4096; i += 256)
    As1s[(i >> 6)*65 + (i & 63)] = As1[i];
  if (t < 64) sp[t] = dots2[(g*64 + t)*2] + dots2[(g*64 + t)*2 + 1];
  __syncthreads();
  if (t < 64) {
    float acc = p1b[0];
    for (int j = 0; j < 64; ++j) acc = fmaf(As1s[t*65 + j], sp[j], acc);
    s[t] = acc;
  }
  __syncthreads();
  if (t < 64) {
    float si = s[t];
    int rank = 0;
    for (int j = 0; j < 64; ++j) {
      float sj = s[j];
      rank += (sj > si) || (sj == si && j < t);
    }
    nidx[g*64 + t] = (rank < K1_) ? rank : -1;
    if (rank < K1_) { perm[rank] = t; gate[rank] = tanhf(si); }
  }
  __syncthreads();
  if (t < K1_) {
    rowsrc[g*K1_ + t]  = g*64 + perm[t];
    rowgate[g*K1_ + t] = gate[t];
  }
}

// ---- gemm2m: xw2 = gathered(y1 f32) @ W2 via 3-limb bf16 MFMA (split in staging) ----
// block: 64 gathered rows x 128 cols, 4 waves; K=256 in 8 steps of 32; 6 MFMA terms
__global__ __launch_bounds__(256) void gemm2m(const float* __restrict__ y1,
                                              const int* __restrict__ rowsrc,
                                              const unsigned short* __restrict__ Whi,
                                              const unsigned short* __restrict__ Wmid,
                                              const unsigned short* __restrict__ Wlo,
                                              float* __restrict__ xw2) {
  __shared__ unsigned short Ahs[64*40], Ams[64*40], Als[64*40];
  __shared__ unsigned short Bhs[128*40], Bms[128*40], Bls[128*40];
  int t = threadIdx.x;
  int row0 = blockIdx.x * 64;
  int w = t >> 6, l = t & 63, lr = l & 15, lg = l >> 4;
  int arow = t >> 2, akq = t & 3;
  size_t asrc = (size_t)rowsrc[row0 + arow] * NHID;
  f32x4_t acc[4][2] = {};
  for (int k0 = 0; k0 < NHID; k0 += 32) {
    {   // stage A: load gathered f32, split into 3 limb planes in-register
      const float* src = y1 + asrc + k0 + akq*8;
      float4 v0 = *(const float4*)(src);
      float4 v1 = *(const float4*)(src + 4);
      float e[8] = {v0.x, v0.y, v0.z, v0.w, v1.x, v1.y, v1.z, v1.w};
      unsigned hq[4], mq[4], lq[4];
#pragma unroll
      for (int jj = 0; jj < 4; ++jj) {
        unsigned short h0,m0,l0,h1,m1,l1;
        split3_bf16(e[2*jj],   h0, m0, l0);
        split3_bf16(e[2*jj+1], h1, m1, l1);
        hq[jj] = (unsigned)h0 | ((unsigned)h1 << 16);
        mq[jj] = (unsigned)m0 | ((unsigned)m1 << 16);
        lq[jj] = (unsigned)l0 | ((unsigned)l1 << 16);
      }
      *(uint4*)&Ahs[arow*40 + akq*8] = make_uint4(hq[0], hq[1], hq[2], hq[3]);
      *(uint4*)&Ams[arow*40 + akq*8] = make_uint4(mq[0], mq[1], mq[2], mq[3]);
      *(uint4*)&Als[arow*40 + akq*8] = make_uint4(lq[0], lq[1], lq[2], lq[3]);
    }
#pragma unroll
    for (int p = 0; p < 2; ++p) {   // stage B: 128 cols x 32 k, 3 planes
      int id = t + p*256;
      int colb = id >> 2, kq = id & 3;
      size_t src = (size_t)colb*256 + k0 + kq*8;
      *(uint4*)&Bhs[colb*40 + kq*8] = *(const uint4*)&Whi[src];
      *(uint4*)&Bms[colb*40 + kq*8] = *(const uint4*)&Wmid[src];
      *(uint4*)&Bls[colb*40 + kq*8] = *(const uint4*)&Wlo[src];
    }
    __syncthreads();
    short8_t ah[4], am[4], al[4], bh[2], bm[2], bl[2];
#pragma unroll
    for (int s = 0; s < 4; ++s) {
      int off = (s*16 + lr)*40 + lg*8;
      ah[s] = *(const short8_t*)&Ahs[off];
      am[s] = *(const short8_t*)&Ams[off];
      al[s] = *(const short8_t*)&Als[off];
    }
#pragma unroll
    for (int t2 = 0; t2 < 2; ++t2) {
      int off = (w*32 + t2*16 + lr)*40 + lg*8;
      bh[t2] = *(const short8_t*)&Bhs[off];
      bm[t2] = *(const short8_t*)&Bms[off];
      bl[t2] = *(const short8_t*)&Bls[off];
    }
#pragma unroll
    for (int s = 0; s < 4; ++s)
#pragma unroll
      for (int t2 = 0; t2 < 2; ++t2) {
        acc[s][t2] = __builtin_amdgcn_mfma_f32_16x16x32_bf16(ah[s], bh[t2], acc[s][t2], 0, 0, 0);
        acc[s][t2] = __builtin_amdgcn_mfma_f32_16x16x32_bf16(ah[s], bm[t2], acc[s][t2], 0, 0, 0);
        acc[s][t2] = __builtin_amdgcn_mfma_f32_16x16x32_bf16(am[s], bh[t2], acc[s][t2], 0, 0, 0);
        acc[s][t2] = __builtin_amdgcn_mfma_f32_16x16x32_bf16(ah[s], bl[t2], acc[s][t2], 0, 0, 0);
        acc[s][t2] = __builtin_amdgcn_mfma_f32_16x16x32_bf16(am[s], bm[t2], acc[s][t2], 0, 0, 0);
        acc[s][t2] = __builtin_amdgcn_mfma_f32_16x16x32_bf16(al[s], bh[t2], acc[s][t2], 0, 0, 0);
      }
    __syncthreads();
  }
#pragma unroll
  for (int s = 0; s < 4; ++s)
#pragma unroll
    for (int t2 = 0; t2 < 2; ++t2)
#pragma unroll
      for (int j = 0; j < 4; ++j) {
        int row_l = s*16 + lg*4 + j;
        int col = w*32 + t2*16 + lr;
        xw2[(size_t)(row0 + row_l)*NOUT + col] = acc[s][t2][j];
      }
}

// ---- mega2r: build A2/As2 + gate-on-load + agg+BN+PReLU + dots + scores + rank-out --
__global__ __launch_bounds__(256) void mega2r(const int* __restrict__ ei,
                                              const float* __restrict__ ew,
                                              const int* __restrict__ nidx,
                                              const float* __restrict__ xw2,
                                              const float* __restrict__ rowgate,
                                              const float* __restrict__ gc2b,
                                              const float* __restrict__ g2,
                                              const float* __restrict__ be2,
                                              const float* __restrict__ mu2,
                                              const float* __restrict__ v2,
                                              const float* __restrict__ pa2,
                                              const float* __restrict__ pw2,
                                              const float* __restrict__ p2b,
                                              float* __restrict__ out) {
  int g = blockIdx.x, t = threadIdx.x;
  __shared__ float A2t[64*68];                 // [j][c] zero-padded
  __shared__ float As2s[K1_*K1_];
  __shared__ __align__(16) float xs[K1_*132];
  __shared__ float dg[K1_], dgs[K1_], dis[K1_], diss[K1_], d[K1_], s[K1_], gA[K1_];
  __shared__ int nm[C_], rankA[K1_];
  __shared__ float4 zpart[8][32];

  for (int i = t; i < 64*68; i += 256) A2t[i] = 0.f;
  for (int i = t; i < K1_*K1_; i += 256) As2s[i] = 0.f;
  if (t < C_) nm[t] = nidx[g*C_ + t];
  if (t < K1_) { dg[t] = 1.f; dgs[t] = 1.f; }
  for (int p = 0; p < 7; ++p) {
    int idx = t + p*256;
    if (idx < K1_*32) {
      int r = idx >> 5, f4 = idx & 31;
      float gt = rowgate[g*K1_ + r];
      float4 v = *(const float4*)(xw2 + ((size_t)g*K1_ + r)*NOUT + f4*4);
      v.x *= gt; v.y *= gt; v.z *= gt; v.w *= gt;
      *(float4*)&xs[r*132 + f4*4] = v;
    }
  }
  int eR[2], eC[2]; float eW[2];
#pragma unroll
  for (int p = 0; p < 2; ++p) {
    int e = t + p*256;
    eR[p] = ei[e]; eC[p] = ei[E_ + e]; eW[p] = ew[e];
  }
  __syncthreads();
  int nr[2], nc[2]; bool val[2];
#pragma unroll
  for (int p = 0; p < 2; ++p) {
    nr[p] = nm[eR[p]]; nc[p] = nm[eC[p]];
    val[p] = (nr[p] >= 0) && (nc[p] >= 0);
    if (val[p]) { atomicAdd(&dg[nc[p]], eW[p]); atomicAdd(&dgs[nc[p]], 1.f); }
  }
  __syncthreads();
  if (t < K1_) { dis[t] = rsqrtf(dg[t]); diss[t] = rsqrtf(dgs[t]); }
  __syncthreads();
#pragma unroll
  for (int p = 0; p < 2; ++p) {
    if (val[p]) {
      atomicAdd(&A2t[nr[p]*68 + nc[p]],  dis[nr[p]] * eW[p] * dis[nc[p]]);
      atomicAdd(&As2s[nc[p]*K1_ + nr[p]], diss[nr[p]] * diss[nc[p]]);
    }
  }
  if (t < K1_) {
    atomicAdd(&A2t[t*68 + t],   dis[t]*dis[t]);
    atomicAdd(&As2s[t*K1_ + t], diss[t]*diss[t]);
  }
  __syncthreads();
  int tx = t & 31, ty = t >> 5;
  float4 scv, shv, pwv;
  {
    int col = 4*tx;
    float4 gv = *(const float4*)(g2 + col);
    float4 vv = *(const float4*)(v2 + col);
    float4 bv = *(const float4*)(be2 + col);
    float4 mv = *(const float4*)(mu2 + col);
    float4 b0 = *(const float4*)(gc2b + col);
    scv.x = gv.x * rsqrtf(vv.x + 1e-5f); scv.y = gv.y * rsqrtf(vv.y + 1e-5f);
    scv.z = gv.z * rsqrtf(vv.z + 1e-5f); scv.w = gv.w * rsqrtf(vv.w + 1e-5f);
    shv = make_float4((b0.x - mv.x)*scv.x + bv.x, (b0.y - mv.y)*scv.y + bv.y,
                      (b0.z - mv.z)*scv.z + bv.z, (b0.w - mv.w)*scv.w + bv.w);
    pwv = *(const float4*)(pw2 + col);
  }
  float a2v = pa2[0];
  float acc[8][4] = {};
  for (int j = 0; j < K1_; ++j) {
    float a[8];
    *(float4*)&a[0] = *(const float4*)&A2t[j*68 + ty*8];
    *(float4*)&a[4] = *(const float4*)&A2t[j*68 + ty*8 + 4];
    float4 xv = *(const float4*)&xs[j*132 + tx*4];
#pragma unroll
    for (int i = 0; i < 8; ++i) {
      acc[i][0] = fmaf(a[i], xv.x, acc[i][0]);
      acc[i][1] = fmaf(a[i], xv.y, acc[i][1]);
      acc[i][2] = fmaf(a[i], xv.z, acc[i][2]);
      acc[i][3] = fmaf(a[i], xv.w, acc[i][3]);
    }
  }
#pragma unroll
  for (int i = 0; i < 8; ++i) {
    int c = ty*8 + i;
    if (c < K1_) {
      float4 o;
      o.x = acc[i][0]*scv.x + shv.x; o.y = acc[i][1]*scv.y + shv.y;
      o.z = acc[i][2]*scv.z + shv.z; o.w = acc[i][3]*scv.w + shv.w;
      o.x = o.x >= 0.f ? o.x : a2v*o.x; o.y = o.y >= 0.f ? o.y : a2v*o.y;
      o.z = o.z >= 0.f ? o.z : a2v*o.z; o.w = o.w >= 0.f ? o.w : a2v*o.w;
      acc[i][0] = o.x; acc[i][1] = o.y; acc[i][2] = o.z; acc[i][3] = o.w;
      float dp = o.x*pwv.x + o.y*pwv.y + o.z*pwv.z + o.w*pwv.w;
      dp += __shfl_xor(dp, 1);
      dp += __shfl_xor(dp, 2);
      dp += __shfl_xor(dp, 4);
      dp += __shfl_xor(dp, 8);
      dp += __shfl_xor(dp, 16);
      if (tx == 0) d[c] = dp;
    }
  }
  __syncthreads();
  if (t < K1_) {
    float sv = p2b[0];
    for (int j = 0; j < K1_; ++j) sv = fmaf(As2s[t*K1_ + j], d[j], sv);
    s[t] = sv;
  }
  __syncthreads();
  if (t < K1_) {
    float si = s[t];
    int rank = 0;
    for (int j = 0; j < K1_; ++j) {
      float sj = s[j];
      rank += (sj > si) || (sj == si && j < t);
    }
    rankA[t] = rank;
    gA[t] = tanhf(si);
  }
  __syncthreads();
  float4 zp = make_float4(0.f, 0.f, 0.f, 0.f);
#pragma unroll
  for (int i = 0; i < 8; ++i) {
    int c = ty*8 + i;
    if (c < K1_) {
      int r = rankA[c];
      if (r < K2_) {
        float gt = gA[c];
        float4 v = make_float4(acc[i][0]*gt, acc[i][1]*gt, acc[i][2]*gt, acc[i][3]*gt);
        *(float4*)(out + ((size_t)g*K2_ + r)*NOUT + 4*tx) = v;
        zp.x += v.x; zp.y += v.y; zp.z += v.z; zp.w += v.w;
      }
    }
  }
  zpart[ty][tx] = zp;
  __syncthreads();
  if (t < 32) {
    float4 z = make_float4(0.f, 0.f, 0.f, 0.f);
#pragma unroll
    for (int k = 0; k < 8; ++k) {
      float4 v = zpart[k][t];
      z.x += v.x; z.y += v.y; z.z += v.z; z.w += v.w;
    }
    const float inv = 1.0f / (float)K2_;
    z.x *= inv; z.y *= inv; z.z *= inv; z.w *= inv;
    *(float4*)(out + (size_t)G_*K2_*NOUT + (size_t)g*NOUT + 4*t) = z;
  }
}

extern "C" void kernel_launch(void* const* d_in, const int* in_sizes, int n_in,
                              void* d_out, int out_size, void* d_ws, size_t ws_size,
                              hipStream_t stream) {
  const float* h    = (const float*)d_in[0];
  const int*   ei   = (const int*)  d_in[1];
  const float* ew   = (const float*)d_in[2];
  const float* gc1w = (const float*)d_in[3];
  const float* gc1b = (const float*)d_in[4];
  const float* bn1g = (const float*)d_in[5];
  const float* bn1b = (const float*)d_in[6];
  const float* bn1m = (const float*)d_in[7];
  const float* bn1v = (const float*)d_in[8];
  const float* pr1a = (const float*)d_in[9];
  const float* p1w  = (const float*)d_in[10];
  const float* p1b  = (const float*)d_in[11];
  const float* gc2w = (const float*)d_in[12];
  const float* gc2b = (const float*)d_in[13];
  const float* bn2g = (const float*)d_in[14];
  const float* bn2b = (const float*)d_in[15];
  const float* bn2m = (const float*)d_in[16];
  const float* bn2v = (const float*)d_in[17];
  const float* pr2a = (const float*)d_in[18];
  const float* p2w  = (const float*)d_in[19];
  const float* p2b  = (const float*)d_in[20];

  float* w = (float*)d_ws;
  // float offsets
  float*          A1      = w;                               // 4096
  float*          As1     = w + 4096;                        // 4096
  float*          dots2   = w + 8192;                        // 131072
  int*            nidx    = (int*)(w + 139264);              // 65536
  int*            rowsrc  = (int*)(w + 204800);              // 53248
  float*          rowgate = w + 258048;                      // 53248
  unsigned short* W1thi   = (unsigned short*)(w + 311296);   // 16384 fl
  unsigned short* W1tlo   = (unsigned short*)(w + 327680);   // 16384 fl
  unsigned short* W2thi   = (unsigned short*)(w + 344064);   // 16384 fl
  unsigned short* W2tmid  = (unsigned short*)(w + 360448);   // 16384 fl
  unsigned short* W2tlo   = (unsigned short*)(w + 376832);   // 16384 fl
  float*          xa2     = w + 393216;                      // 8388608
  unsigned short* xahi    = (unsigned short*)(w + 8781824);  // 4194304 fl
  unsigned short* xalo    = (unsigned short*)(w + 12976128); // 4194304 fl
  float*          y1      = w + 17170432;                    // 16777216 fl -> 33947648
  float*          xw2     = xa2;   // xa2 dead after xa_cvt

  build_A1<<<1, 256, 0, stream>>>(ei, ew, A1, As1);
  w1prep<<<64, 256, 0, stream>>>(gc1w, W1thi, W1tlo);
  w2prep<<<64, 256, 0, stream>>>(gc2w, W2thi, W2tmid, W2tlo);
  preagg_b<<<1024, 256, 0, stream>>>(h, A1, xa2);
  xa_cvt<<<1024, 256, 0, stream>>>(xa2, xahi, xalo);
  gemm1m<<<dim3(1024, 2), 256, 0, stream>>>(xahi, xalo, W1thi, W1tlo, gc1b,
                                            bn1g, bn1b, bn1m, bn1v, pr1a, p1w,
                                            y1, dots2);
  pool1s<<<G_, 256, 0, stream>>>(dots2, As1, p1b, rowsrc, rowgate, nidx);
  gemm2m<<<832, 256, 0, stream>>>(y1, rowsrc, W2thi, W2tmid, W2tlo, xw2);
  mega2r<<<G_, 256, 0, stream>>>(ei, ew, nidx, xw2, rowgate, gc2b, bn2g, bn2b,
                                 bn2m, bn2v, pr2a, p2w, p2b, (float*)d_out);
}

// Round 12
// 138.299 us; speedup vs baseline: 2.3921x; 1.0679x over previous
//
#include <hip/hip_runtime.h>
#include <math.h>

#define B_   32
#define C_   64
#define F_   128
#define TP_  32
#define G_   (B_*TP_)      // 1024 graphs
#define NHID 256
#define NOUT 128
#define E_   512
#define K1_  52            // ceil(0.8*64)
#define K2_  42            // ceil(0.8*52)

typedef __attribute__((ext_vector_type(8))) short short8_t;   // 8 bf16 (4 VGPR)
typedef __attribute__((ext_vector_type(4))) float f32x4_t;

__device__ __forceinline__ void split_bf16(float v, unsigned short &h, unsigned short &l) {
  unsigned u = __float_as_uint(v);
  unsigned hb = (u + 0x7FFFu + ((u >> 16) & 1u)) & 0xFFFF0000u;  // RNE bf16 of v
  float hf = __uint_as_float(hb);
  float r = v - hf;                                              // exact in f32
  unsigned ur = __float_as_uint(r);
  unsigned lb = (ur + 0x7FFFu + ((ur >> 16) & 1u)) >> 16;        // RNE bf16 of r
  h = (unsigned short)(hb >> 16);
  l = (unsigned short)lb;
}

__device__ __forceinline__ void split3_bf16(float v, unsigned short &h,
                                            unsigned short &m, unsigned short &l) {
  unsigned u = __float_as_uint(v);
  unsigned hb = (u + 0x7FFFu + ((u >> 16) & 1u)) & 0xFFFF0000u;
  float hf = __uint_as_float(hb);
  float r1 = v - hf;                                             // exact
  unsigned u1 = __float_as_uint(r1);
  unsigned mb = (u1 + 0x7FFFu + ((u1 >> 16) & 1u)) & 0xFFFF0000u;
  float mf = __uint_as_float(mb);
  float r2 = r1 - mf;                                            // exact
  unsigned u2 = __float_as_uint(r2);
  unsigned lb = (u2 + 0x7FFFu + ((u2 >> 16) & 1u)) >> 16;
  h = (unsigned short)(hb >> 16);
  m = (unsigned short)(mb >> 16);
  l = (unsigned short)lb;
}

// -------- build shared 64x64 A1 (edge-weight norm) and As1 (binary norm) -------------
__global__ __launch_bounds__(256) void build_A1(const int* __restrict__ ei,
                                                const float* __restrict__ ew,
                                                float* __restrict__ A1,
                                                float* __restrict__ As1) {
  __shared__ float A1s[C_*C_], As1s[C_*C_];
  __shared__ float dg[C_], dgs[C_], dis[C_], diss[C_];
  int t = threadIdx.x;
  for (int i = t; i < C_*C_; i += 256) { A1s[i] = 0.f; As1s[i] = 0.f; }
  if (t < C_) { dg[t] = 1.f; dgs[t] = 1.f; }   // self-loop weight 1
  int r0[2], c0[2]; float w0[2];
#pragma unroll
  for (int p = 0; p < 2; ++p) {
    int e = t + p*256;
    r0[p] = ei[e]; c0[p] = ei[E_ + e]; w0[p] = ew[e];
  }
  __syncthreads();
#pragma unroll
  for (int p = 0; p < 2; ++p) {
    atomicAdd(&dg[c0[p]], w0[p]);
    atomicAdd(&dgs[c0[p]], 1.f);
  }
  __syncthreads();
  if (t < C_) { dis[t] = rsqrtf(dg[t]); diss[t] = rsqrtf(dgs[t]); }
  __syncthreads();
#pragma unroll
  for (int p = 0; p < 2; ++p) {
    int r = r0[p], c = c0[p];
    atomicAdd(&A1s[c*C_ + r],  dis[r] * w0[p] * dis[c]);
    atomicAdd(&As1s[c*C_ + r], diss[r] * diss[c]);
  }
  if (t < C_) {
    atomicAdd(&A1s[t*C_ + t],  dis[t] * dis[t]);
    atomicAdd(&As1s[t*C_ + t], diss[t] * diss[t]);
  }
  __syncthreads();
  for (int i = t; i < C_*C_; i += 256) { A1[i] = A1s[i]; As1[i] = As1s[i]; }
}

// ---- w1prep: W1 [k 128][col 256] f32 -> W1t hi/lo [col][k] bf16 ----------------------
__global__ __launch_bounds__(256) void w1prep(const float* __restrict__ W1,
                                              unsigned short* __restrict__ Whi,
                                              unsigned short* __restrict__ Wlo) {
  int tid = blockIdx.x*256 + threadIdx.x;     // 16384 threads, 2 k's each
  int col = tid >> 6, k2 = tid & 63;
  float v0 = W1[(size_t)(2*k2)*NHID + col];
  float v1 = W1[(size_t)(2*k2+1)*NHID + col];
  unsigned short h0,l0,h1,l1;
  split_bf16(v0, h0, l0);
  split_bf16(v1, h1, l1);
  *(unsigned*)&Whi[(size_t)col*128 + 2*k2] = (unsigned)h0 | ((unsigned)h1 << 16);
  *(unsigned*)&Wlo[(size_t)col*128 + 2*k2] = (unsigned)l0 | ((unsigned)l1 << 16);
}

// ---- w2prep: W2 [k 256][col 128] f32 -> W2t hi/mid/lo [col][k 256] bf16 --------------
__global__ __launch_bounds__(256) void w2prep(const float* __restrict__ W2,
                                              unsigned short* __restrict__ Whi,
                                              unsigned short* __restrict__ Wmid,
                                              unsigned short* __restrict__ Wlo) {
  int tid = blockIdx.x*256 + threadIdx.x;     // 16384 threads, 2 k's each
  int col = tid >> 7, k2 = tid & 127;
  float v0 = W2[(size_t)(2*k2)*NOUT + col];
  float v1 = W2[(size_t)(2*k2+1)*NOUT + col];
  unsigned short h0,m0,l0,h1,m1,l1;
  split3_bf16(v0, h0, m0, l0);
  split3_bf16(v1, h1, m1, l1);
  *(unsigned*)&Whi [(size_t)col*256 + 2*k2] = (unsigned)h0 | ((unsigned)h1 << 16);
  *(unsigned*)&Wmid[(size_t)col*256 + 2*k2] = (unsigned)m0 | ((unsigned)m1 << 16);
  *(unsigned*)&Wlo [(size_t)col*256 + 2*k2] = (unsigned)l0 | ((unsigned)l1 << 16);
}

// ---- preagg: xa2[b,c,f,tp] = sum_j A1[c,j] * h[b,j,f,tp]  (per-b, (f,tp) cols) ------
__global__ __launch_bounds__(256) void preagg_b(const float* __restrict__ h,
                                                const float* __restrict__ A1,
                                                float* __restrict__ xa2) {
  int bid = blockIdx.x; int b = bid >> 5, q = bid & 31;   // q: 128-col chunk of 4096
  __shared__ float At[64*68];                              // A1 transposed [j][c]
  __shared__ __align__(16) float Hs[64*132];
  int t = threadIdx.x;
#pragma unroll
  for (int p = 0; p < 16; ++p) {
    int m = t + p*256;                      // A1[c*64+j]
    At[(m & 63)*68 + (m >> 6)] = A1[m];
  }
  const float* hb = h + ((size_t)b*64)*4096 + q*128;
#pragma unroll
  for (int p = 0; p < 8; ++p) {
    int idx = t + p*256;                    // 2048 float4 tiles: 64 j x 32 f4
    int j = idx >> 5, f4 = idx & 31;
    *(float4*)&Hs[j*132 + f4*4] = *(const float4*)(hb + (size_t)j*4096 + f4*4);
  }
  __syncthreads();
  int tx = t & 31, ty = t >> 5;             // tx: f4 col, ty: 8-row c block
  float acc[8][4] = {};
  for (int j = 0; j < 64; ++j) {
    float a[8];
    *(float4*)&a[0] = *(const float4*)&At[j*68 + ty*8];
    *(float4*)&a[4] = *(const float4*)&At[j*68 + ty*8 + 4];
    float4 hv = *(const float4*)&Hs[j*132 + tx*4];
#pragma unroll
    for (int i = 0; i < 8; ++i) {
      acc[i][0] = fmaf(a[i], hv.x, acc[i][0]);
      acc[i][1] = fmaf(a[i], hv.y, acc[i][1]);
      acc[i][2] = fmaf(a[i], hv.z, acc[i][2]);
      acc[i][3] = fmaf(a[i], hv.w, acc[i][3]);
    }
  }
  float* outp = xa2 + (((size_t)b*64) << 12) + q*128 + tx*4;
#pragma unroll
  for (int i = 0; i < 8; ++i) {
    int c = ty*8 + i;
    *(float4*)(outp + ((size_t)c << 12)) =
        make_float4(acc[i][0], acc[i][1], acc[i][2], acc[i][3]);
  }
}

// ---- xa_cvt: xa2 [b][c][f][tp] f32 -> xahi/xalo [R][k=f] bf16, R=(b*32+tp)*64+c -----
__global__ __launch_bounds__(256) void xa_cvt(const float* __restrict__ xa2,
                                              unsigned short* __restrict__ xahi,
                                              unsigned short* __restrict__ xalo) {
  int bid = blockIdx.x;                      // 1024: b = bid>>5, cpair
  int b = bid >> 5, c0 = (bid & 31) * 2;
  __shared__ float xs[8192];                 // [c_l 2][f 128][tp 32]
  int t = threadIdx.x;
  const float* src = xa2 + ((size_t)(b*64 + c0) << 12);
#pragma unroll
  for (int p = 0; p < 8; ++p) {
    int idx = (t + p*256) * 4;
    *(float4*)&xs[idx] = *(const float4*)(src + idx);
  }
  __syncthreads();
  int row_l = t >> 2, fq = t & 3;            // row_l = c_l*32+tp
  int c_l = row_l >> 5, tp = row_l & 31;
  size_t R = ((size_t)b*32 + tp)*64 + c0 + c_l;
  const float* base = &xs[c_l*4096 + tp];
#pragma unroll
  for (int i = 0; i < 4; ++i) {
    int f8 = fq + 4*i;
    unsigned hp[4], lp[4];
#pragma unroll
    for (int jj = 0; jj < 4; ++jj) {
      unsigned short h0,l0,h1,l1;
      split_bf16(base[(f8*8 + 2*jj    )*32], h0, l0);
      split_bf16(base[(f8*8 + 2*jj + 1)*32], h1, l1);
      hp[jj] = (unsigned)h0 | ((unsigned)h1 << 16);
      lp[jj] = (unsigned)l0 | ((unsigned)l1 << 16);
    }
    *(uint4*)&xahi[R*128 + f8*8] = make_uint4(hp[0], hp[1], hp[2], hp[3]);
    *(uint4*)&xalo[R*128 + f8*8] = make_uint4(lp[0], lp[1], lp[2], lp[3]);
  }
}

// ---- gemm1m: y1 = prelu(bn(xa @ W1 + b1)) via bf16x3 MFMA; y1 out as f32 ------------
__global__ __launch_bounds__(256) void gemm1m(const unsigned short* __restrict__ xahi,
                                              const unsigned short* __restrict__ xalo,
                                              const unsigned short* __restrict__ Whi,
                                              const unsigned short* __restrict__ Wlo,
                                              const float* __restrict__ gc1b,
                                              const float* __restrict__ g1,
                                              const float* __restrict__ be1,
                                              const float* __restrict__ mu1,
                                              const float* __restrict__ v1,
                                              const float* __restrict__ pa1,
                                              const float* __restrict__ pw1,
                                              float* __restrict__ y1,
                                              float* __restrict__ dots2) {
  __shared__ unsigned short Ahs[64*40], Als[64*40];     // [row][k32 pad40]
  __shared__ unsigned short Bhs[128*40], Bls[128*40];   // [col][k32 pad40]
  __shared__ float dsum[64*4];
  int t = threadIdx.x;
  int row0 = blockIdx.x * 64;
  int colhalf = blockIdx.y;
  int w = t >> 6, l = t & 63, lr = l & 15, lg = l >> 4;
  f32x4_t acc[4][2] = {};
  for (int k0 = 0; k0 < 128; k0 += 32) {
    {   // stage A: 64 rows x 32 k, 16B chunk per thread per plane
      int row = t >> 2, kq = t & 3;
      size_t src = (size_t)(row0 + row)*128 + k0 + kq*8;
      *(uint4*)&Ahs[row*40 + kq*8] = *(const uint4*)&xahi[src];
      *(uint4*)&Als[row*40 + kq*8] = *(const uint4*)&xalo[src];
    }
#pragma unroll
    for (int p = 0; p < 2; ++p) {   // stage B: 128 cols x 32 k
      int id = t + p*256;
      int colb = id >> 2, kq = id & 3;
      size_t src = (size_t)(colhalf*128 + colb)*128 + k0 + kq*8;
      *(uint4*)&Bhs[colb*40 + kq*8] = *(const uint4*)&Whi[src];
      *(uint4*)&Bls[colb*40 + kq*8] = *(const uint4*)&Wlo[src];
    }
    __syncthreads();
    short8_t ah[4], al[4], bh[2], bl[2];
#pragma unroll
    for (int s = 0; s < 4; ++s) {
      int off = (s*16 + lr)*40 + lg*8;
      ah[s] = *(const short8_t*)&Ahs[off];
      al[s] = *(const short8_t*)&Als[off];
    }
#pragma unroll
    for (int t2 = 0; t2 < 2; ++t2) {
      int off = (w*32 + t2*16 + lr)*40 + lg*8;
      bh[t2] = *(const short8_t*)&Bhs[off];
      bl[t2] = *(const short8_t*)&Bls[off];
    }
#pragma unroll
    for (int s = 0; s < 4; ++s)
#pragma unroll
      for (int t2 = 0; t2 < 2; ++t2) {
        acc[s][t2] = __builtin_amdgcn_mfma_f32_16x16x32_bf16(ah[s], bh[t2], acc[s][t2], 0, 0, 0);
        acc[s][t2] = __builtin_amdgcn_mfma_f32_16x16x32_bf16(al[s], bh[t2], acc[s][t2], 0, 0, 0);
        acc[s][t2] = __builtin_amdgcn_mfma_f32_16x16x32_bf16(ah[s], bl[t2], acc[s][t2], 0, 0, 0);
      }
    __syncthreads();
  }
  // epilogue: BN + PReLU + y1 (f32) write + pool dot partials
  float sc_[2], sh_[2], pw_[2];
#pragma unroll
  for (int t2 = 0; t2 < 2; ++t2) {
    int col_g = colhalf*128 + w*32 + t2*16 + lr;
    float s = g1[col_g] * rsqrtf(v1[col_g] + 1e-5f);
    sc_[t2] = s;
    sh_[t2] = (gc1b[col_g] - mu1[col_g])*s + be1[col_g];
    pw_[t2] = pw1[col_g];
  }
  float a1v = pa1[0];
#pragma unroll
  for (int s = 0; s < 4; ++s)
#pragma unroll
    for (int j = 0; j < 4; ++j) {
      int row_l = s*16 + lg*4 + j;
      size_t R = (size_t)row0 + row_l;
      float d = 0.f;
#pragma unroll
      for (int t2 = 0; t2 < 2; ++t2) {
        float o = acc[s][t2][j]*sc_[t2] + sh_[t2];
        o = o >= 0.f ? o : a1v*o;
        y1[R*NHID + colhalf*128 + w*32 + t2*16 + lr] = o;
        d += o * pw_[t2];
      }
      d += __shfl_xor(d, 1);
      d += __shfl_xor(d, 2);
      d += __shfl_xor(d, 4);
      d += __shfl_xor(d, 8);
      if (lr == 0) dsum[row_l*4 + w] = d;
    }
  __syncthreads();
  if (t < 64)
    dots2[((size_t)row0 + t)*2 + colhalf] =
        (dsum[t*4+0] + dsum[t*4+1]) + (dsum[t*4+2] + dsum[t*4+3]);
}

// ---- pool1s: scores = As1 @ dots + b; stable top-52; emit rowsrc/rowgate/nidx -------
__global__ __launch_bounds__(256) void pool1s(const float* __restrict__ dots2,
                                              const float* __restrict__ As1,
                                              const float* __restrict__ p1b,
                                              int* __restrict__ rowsrc,
                                              float* __restrict__ rowgate,
                                              int* __restrict__ nidx) {
  int g = blockIdx.x, t = threadIdx.x;
  __shared__ float As1s[64*65];
  __shared__ float sp[64], s[64];
  __shared__ int perm[K1_];
  __shared__ float gate[K1_];
  for (int i = t; i < 4096; i += 256)
    As1s[(i >> 6)*65 + (i & 63)] = As1[i];
  if (t < 64) sp[t] = dots2[(g*64 + t)*2] + dots2[(g*64 + t)*2 + 1];
  __syncthreads();
  if (t < 64) {
    float acc = p1b[0];
    for (int j = 0; j < 64; ++j) acc = fmaf(As1s[t*65 + j], sp[j], acc);
    s[t] = acc;
  }
  __syncthreads();
  if (t < 64) {
    float si = s[t];
    int rank = 0;
    for (int j = 0; j < 64; ++j) {
      float sj = s[j];
      rank += (sj > si) || (sj == si && j < t);
    }
    nidx[g*64 + t] = (rank < K1_) ? rank : -1;
    if (rank < K1_) { perm[rank] = t; gate[rank] = tanhf(si); }
  }
  __syncthreads();
  if (t < K1_) {
    rowsrc[g*K1_ + t]  = g*64 + perm[t];
    rowgate[g*K1_ + t] = gate[t];
  }
}

// ---- mega2f: per-graph fused layer 2 ------------------------------------------------
// phase 1: 3-limb MFMA  xs = (gate*gathered y1) @ W2   (52 rows pad 64, 128 cols, K=256)
// phase 2: build A2/As2 + agg + BN/PReLU + dots + scores + topk + rank-directed output
__global__ __launch_bounds__(256) void mega2f(const float* __restrict__ y1,
                                              const int* __restrict__ rowsrc,
                                              const float* __restrict__ rowgate,
                                              const unsigned short* __restrict__ Whi,
                                              const unsigned short* __restrict__ Wmid,
                                              const unsigned short* __restrict__ Wlo,
                                              const int* __restrict__ ei,
                                              const float* __restrict__ ew,
                                              const int* __restrict__ nidx,
                                              const float* __restrict__ gc2b,
                                              const float* __restrict__ g2,
                                              const float* __restrict__ be2,
                                              const float* __restrict__ mu2,
                                              const float* __restrict__ v2,
                                              const float* __restrict__ pa2,
                                              const float* __restrict__ pw2,
                                              const float* __restrict__ p2b,
                                              float* __restrict__ out) {
  __shared__ __align__(16) char pool[51584];
  // phase-1 aliases (46080 B)
  unsigned short* Ahs = (unsigned short*)(pool);
  unsigned short* Ams = (unsigned short*)(pool + 5120);
  unsigned short* Als = (unsigned short*)(pool + 10240);
  unsigned short* Bhs = (unsigned short*)(pool + 15360);
  unsigned short* Bms = (unsigned short*)(pool + 25600);
  unsigned short* Bls = (unsigned short*)(pool + 35840);
  // phase-2 aliases (51584 B)
  float* xs   = (float*)(pool);            // 52*132*4 = 27456
  float* A2t  = (float*)(pool + 27456);    // [j 52][c 64] = 13312
  float* As2s = (float*)(pool + 40768);    // [c 52][j 52] = 10816
  float4* zpart = (float4*)(pool);         // 4096, aliases xs (dead by then)
  __shared__ float dg[K1_], dgs[K1_], dis[K1_], diss[K1_], d[K1_], s[K1_], gA[K1_];
  __shared__ int nm[C_], rankA[K1_];

  int t = threadIdx.x, g = blockIdx.x;
  int w = t >> 6, l = t & 63, lr = l & 15, lg = l >> 4;
  // ---------------- phase 1: MFMA ----------------
  int arow = t >> 2, akq = t & 3;
  int ar = (arow < K1_) ? arow : 0;
  size_t asrc = (size_t)rowsrc[g*K1_ + ar] * NHID;
  float gt = rowgate[g*K1_ + ar];
  f32x4_t macc[4][2] = {};
  for (int k0 = 0; k0 < NHID; k0 += 32) {
    {   // stage A: gather f32, gate, split3 into limb planes
      const float* src = y1 + asrc + k0 + akq*8;
      float4 v0 = *(const float4*)(src);
      float4 v1 = *(const float4*)(src + 4);
      float e[8] = {v0.x, v0.y, v0.z, v0.w, v1.x, v1.y, v1.z, v1.w};
      unsigned hq[4], mq[4], lq[4];
#pragma unroll
      for (int jj = 0; jj < 4; ++jj) {
        unsigned short h0,m0,l0,h1,m1,l1;
        split3_bf16(gt * e[2*jj],   h0, m0, l0);
        split3_bf16(gt * e[2*jj+1], h1, m1, l1);
        hq[jj] = (unsigned)h0 | ((unsigned)h1 << 16);
        mq[jj] = (unsigned)m0 | ((unsigned)m1 << 16);
        lq[jj] = (unsigned)l0 | ((unsigned)l1 << 16);
      }
      *(uint4*)&Ahs[arow*40 + akq*8] = make_uint4(hq[0], hq[1], hq[2], hq[3]);
      *(uint4*)&Ams[arow*40 + akq*8] = make_uint4(mq[0], mq[1], mq[2], mq[3]);
      *(uint4*)&Als[arow*40 + akq*8] = make_uint4(lq[0], lq[1], lq[2], lq[3]);
    }
#pragma unroll
    for (int p = 0; p < 2; ++p) {   // stage B: 128 cols x 32 k, 3 planes
      int id = t + p*256;
      int colb = id >> 2, kq = id & 3;
      size_t src = (size_t)colb*256 + k0 + kq*8;
      *(uint4*)&Bhs[colb*40 + kq*8] = *(const uint4*)&Whi[src];
      *(uint4*)&Bms[colb*40 + kq*8] = *(const uint4*)&Wmid[src];
      *(uint4*)&Bls[colb*40 + kq*8] = *(const uint4*)&Wlo[src];
    }
    __syncthreads();
    short8_t ah[4], am[4], al[4], bh[2], bm[2], bl[2];
#pragma unroll
    for (int ss = 0; ss < 4; ++ss) {
      int off = (ss*16 + lr)*40 + lg*8;
      ah[ss] = *(const short8_t*)&Ahs[off];
      am[ss] = *(const short8_t*)&Ams[off];
      al[ss] = *(const short8_t*)&Als[off];
    }
#pragma unroll
    for (int t2 = 0; t2 < 2; ++t2) {
      int off = (w*32 + t2*16 + lr)*40 + lg*8;
      bh[t2] = *(const short8_t*)&Bhs[off];
      bm[t2] = *(const short8_t*)&Bms[off];
      bl[t2] = *(const short8_t*)&Bls[off];
    }
#pragma unroll
    for (int ss = 0; ss < 4; ++ss)
#pragma unroll
      for (int t2 = 0; t2 < 2; ++t2) {
        macc[ss][t2] = __builtin_amdgcn_mfma_f32_16x16x32_bf16(ah[ss], bh[t2], macc[ss][t2], 0, 0, 0);
        macc[ss][t2] = __builtin_amdgcn_mfma_f32_16x16x32_bf16(ah[ss], bm[t2], macc[ss][t2], 0, 0, 0);
        macc[ss][t2] = __builtin_amdgcn_mfma_f32_16x16x32_bf16(am[ss], bh[t2], macc[ss][t2], 0, 0, 0);
        macc[ss][t2] = __builtin_amdgcn_mfma_f32_16x16x32_bf16(ah[ss], bl[t2], macc[ss][t2], 0, 0, 0);
        macc[ss][t2] = __builtin_amdgcn_mfma_f32_16x16x32_bf16(am[ss], bm[t2], macc[ss][t2], 0, 0, 0);
        macc[ss][t2] = __builtin_amdgcn_mfma_f32_16x16x32_bf16(al[ss], bh[t2], macc[ss][t2], 0, 0, 0);
      }
    __syncthreads();
  }
  // ---------------- phase 2 setup: xs <- macc; build A2/As2 ----------------
#pragma unroll
  for (int ss = 0; ss < 4; ++ss)
#pragma unroll
    for (int t2 = 0; t2 < 2; ++t2)
#pragma unroll
      for (int j = 0; j < 4; ++j) {
        int row_l = ss*16 + lg*4 + j;
        if (row_l < K1_)
          xs[row_l*132 + w*32 + t2*16 + lr] = macc[ss][t2][j];
      }
  for (int i = t; i < K1_*64; i += 256) A2t[i] = 0.f;
  for (int i = t; i < K1_*K1_; i += 256) As2s[i] = 0.f;
  if (t < C_) nm[t] = nidx[g*C_ + t];
  if (t < K1_) { dg[t] = 1.f; dgs[t] = 1.f; }
  int eR[2], eC[2]; float eW[2];
#pragma unroll
  for (int p = 0; p < 2; ++p) {
    int e = t + p*256;
    eR[p] = ei[e]; eC[p] = ei[E_ + e]; eW[p] = ew[e];
  }
  __syncthreads();
  int nr[2], nc[2]; bool val[2];
#pragma unroll
  for (int p = 0; p < 2; ++p) {
    nr[p] = nm[eR[p]]; nc[p] = nm[eC[p]];
    val[p] = (nr[p] >= 0) && (nc[p] >= 0);
    if (val[p]) { atomicAdd(&dg[nc[p]], eW[p]); atomicAdd(&dgs[nc[p]], 1.f); }
  }
  __syncthreads();
  if (t < K1_) { dis[t] = rsqrtf(dg[t]); diss[t] = rsqrtf(dgs[t]); }
  __syncthreads();
#pragma unroll
  for (int p = 0; p < 2; ++p) {
    if (val[p]) {
      atomicAdd(&A2t[nr[p]*64 + nc[p]],   dis[nr[p]] * eW[p] * dis[nc[p]]);
      atomicAdd(&As2s[nc[p]*K1_ + nr[p]], diss[nr[p]] * diss[nc[p]]);
    }
  }
  if (t < K1_) {
    atomicAdd(&A2t[t*64 + t],   dis[t]*dis[t]);
    atomicAdd(&As2s[t*K1_ + t], diss[t]*diss[t]);
  }
  __syncthreads();
  // ---------------- agg + BN + PReLU + dots ----------------
  int tx = t & 31, ty = t >> 5;
  float4 scv, shv, pwv;
  {
    int col = 4*tx;
    float4 gv = *(const float4*)(g2 + col);
    float4 vv = *(const float4*)(v2 + col);
    float4 bv = *(const float4*)(be2 + col);
    float4 mv = *(const float4*)(mu2 + col);
    float4 b0 = *(const float4*)(gc2b + col);
    scv.x = gv.x * rsqrtf(vv.x + 1e-5f); scv.y = gv.y * rsqrtf(vv.y + 1e-5f);
    scv.z = gv.z * rsqrtf(vv.z + 1e-5f); scv.w = gv.w * rsqrtf(vv.w + 1e-5f);
    shv = make_float4((b0.x - mv.x)*scv.x + bv.x, (b0.y - mv.y)*scv.y + bv.y,
                      (b0.z - mv.z)*scv.z + bv.z, (b0.w - mv.w)*scv.w + bv.w);
    pwv = *(const float4*)(pw2 + col);
  }
  float a2v = pa2[0];
  float aacc[8][4] = {};
  for (int j = 0; j < K1_; ++j) {
    float a[8];
    *(float4*)&a[0] = *(const float4*)&A2t[j*64 + ty*8];
    *(float4*)&a[4] = *(const float4*)&A2t[j*64 + ty*8 + 4];
    float4 xv = *(const float4*)&xs[j*132 + tx*4];
#pragma unroll
    for (int i = 0; i < 8; ++i) {
      aacc[i][0] = fmaf(a[i], xv.x, aacc[i][0]);
      aacc[i][1] = fmaf(a[i], xv.y, aacc[i][1]);
      aacc[i][2] = fmaf(a[i], xv.z, aacc[i][2]);
      aacc[i][3] = fmaf(a[i], xv.w, aacc[i][3]);
    }
  }
#pragma unroll
  for (int i = 0; i < 8; ++i) {
    int c = ty*8 + i;
    if (c < K1_) {
      float4 o;
      o.x = aacc[i][0]*scv.x + shv.x; o.y = aacc[i][1]*scv.y + shv.y;
      o.z = aacc[i][2]*scv.z + shv.z; o.w = aacc[i][3]*scv.w + shv.w;
      o.x = o.x >= 0.f ? o.x : a2v*o.x; o.y = o.y >= 0.f ? o.y : a2v*o.y;
      o.z = o.z >= 0.f ? o.z : a2v*o.z; o.w = o.w >= 0.f ? o.w : a2v*o.w;
      aacc[i][0] = o.x; aacc[i][1] = o.y; aacc[i][2] = o.z; aacc[i][3] = o.w;
      float dp = o.x*pwv.x + o.y*pwv.y + o.z*pwv.z + o.w*pwv.w;
      dp += __shfl_xor(dp, 1);
      dp += __shfl_xor(dp, 2);
      dp += __shfl_xor(dp, 4);
      dp += __shfl_xor(dp, 8);
      dp += __shfl_xor(dp, 16);
      if (tx == 0) d[c] = dp;
    }
  }
  __syncthreads();
  if (t < K1_) {
    float sv = p2b[0];
    for (int j = 0; j < K1_; ++j) sv = fmaf(As2s[t*K1_ + j], d[j], sv);
    s[t] = sv;
  }
  __syncthreads();
  if (t < K1_) {
    float si = s[t];
    int rank = 0;
    for (int j = 0; j < K1_; ++j) {
      float sj = s[j];
      rank += (sj > si) || (sj == si && j < t);
    }
    rankA[t] = rank;
    gA[t] = tanhf(si);
  }
  __syncthreads();
  // ---------------- rank-directed output + mean ----------------
  float4 zp = make_float4(0.f, 0.f, 0.f, 0.f);
#pragma unroll
  for (int i = 0; i < 8; ++i) {
    int c = ty*8 + i;
    if (c < K1_) {
      int r = rankA[c];
      if (r < K2_) {
        float gv = gA[c];
        float4 v = make_float4(aacc[i][0]*gv, aacc[i][1]*gv, aacc[i][2]*gv, aacc[i][3]*gv);
        *(float4*)(out + ((size_t)g*K2_ + r)*NOUT + 4*tx) = v;
        zp.x += v.x; zp.y += v.y; zp.z += v.z; zp.w += v.w;
      }
    }
  }
  __syncthreads();          // xs (aliased by zpart) fully dead
  zpart[ty*32 + tx] = zp;
  __syncthreads();
  if (t < 32) {
    float4 z = make_float4(0.f, 0.f, 0.f, 0.f);
#pragma unroll
    for (int k = 0; k < 8; ++k) {
      float4 v = zpart[k*32 + t];
      z.x += v.x; z.y += v.y; z.z += v.z; z.w += v.w;
    }
    const float inv = 1.0f / (float)K2_;
    z.x *= inv; z.y *= inv; z.z *= inv; z.w *= inv;
    *(float4*)(out + (size_t)G_*K2_*NOUT + (size_t)g*NOUT + 4*t) = z;
  }
}

extern "C" void kernel_launch(void* const* d_in, const int* in_sizes, int n_in,
                              void* d_out, int out_size, void* d_ws, size_t ws_size,
                              hipStream_t stream) {
  const float* h    = (const float*)d_in[0];
  const int*   ei   = (const int*)  d_in[1];
  const float* ew   = (const float*)d_in[2];
  const float* gc1w = (const float*)d_in[3];
  const float* gc1b = (const float*)d_in[4];
  const float* bn1g = (const float*)d_in[5];
  const float* bn1b = (const float*)d_in[6];
  const float* bn1m = (const float*)d_in[7];
  const float* bn1v = (const float*)d_in[8];
  const float* pr1a = (const float*)d_in[9];
  const float* p1w  = (const float*)d_in[10];
  const float* p1b  = (const float*)d_in[11];
  const float* gc2w = (const float*)d_in[12];
  const float* gc2b = (const float*)d_in[13];
  const float* bn2g = (const float*)d_in[14];
  const float* bn2b = (const float*)d_in[15];
  const float* bn2m = (const float*)d_in[16];
  const float* bn2v = (const float*)d_in[17];
  const float* pr2a = (const float*)d_in[18];
  const float* p2w  = (const float*)d_in[19];
  const float* p2b  = (const float*)d_in[20];

  float* w = (float*)d_ws;
  // float offsets
  float*          A1      = w;                               // 4096
  float*          As1     = w + 4096;                        // 4096
  float*          dots2   = w + 8192;                        // 131072
  int*            nidx    = (int*)(w + 139264);              // 65536
  int*            rowsrc  = (int*)(w + 204800);              // 53248
  float*          rowgate = w + 258048;                      // 53248
  unsigned short* W1thi   = (unsigned short*)(w + 311296);   // 16384 fl
  unsigned short* W1tlo   = (unsigned short*)(w + 327680);   // 16384 fl
  unsigned short* W2thi   = (unsigned short*)(w + 344064);   // 16384 fl
  unsigned short* W2tmid  = (unsigned short*)(w + 360448);   // 16384 fl
  unsigned short* W2tlo   = (unsigned short*)(w + 376832);   // 16384 fl
  float*          xa2     = w + 393216;                      // 8388608
  unsigned short* xahi    = (unsigned short*)(w + 8781824);  // 4194304 fl
  unsigned short* xalo    = (unsigned short*)(w + 12976128); // 4194304 fl
  float*          y1      = w + 17170432;                    // 16777216 fl -> 33947648

  build_A1<<<1, 256, 0, stream>>>(ei, ew, A1, As1);
  w1prep<<<64, 256, 0, stream>>>(gc1w, W1thi, W1tlo);
  w2prep<<<64, 256, 0, stream>>>(gc2w, W2thi, W2tmid, W2tlo);
  preagg_b<<<1024, 256, 0, stream>>>(h, A1, xa2);
  xa_cvt<<<1024, 256, 0, stream>>>(xa2, xahi, xalo);
  gemm1m<<<dim3(1024, 2), 256, 0, stream>>>(xahi, xalo, W1thi, W1tlo, gc1b,
                                            bn1g, bn1b, bn1m, bn1v, pr1a, p1w,
                                            y1, dots2);
  pool1s<<<G_, 256, 0, stream>>>(dots2, As1, p1b, rowsrc, rowgate, nidx);
  mega2f<<<G_, 256, 0, stream>>>(y1, rowsrc, rowgate, W2thi, W2tmid, W2tlo,
                                 ei, ew, nidx, gc2b, bn2g, bn2b, bn2m, bn2v,
                                 pr2a, p2w, p2b, (float*)d_out);
}